// Round 20
// baseline (353.835 us; speedup 1.0000x reference)
//
#include <hip/hip_runtime.h>

typedef unsigned short u16;
typedef unsigned int   u32;
typedef __attribute__((ext_vector_type(8)))  _Float16 f16x8;
typedef __attribute__((ext_vector_type(2)))  __fp16   fp16x2;
typedef __attribute__((ext_vector_type(4)))  float    f32x4;
typedef __attribute__((ext_vector_type(16))) float    f32x16;

#define LOG2E 1.44269504088896340f

__device__ __forceinline__ u16 f2h(float x) {
  union { _Float16 h; u16 u; } c;
  c.h = (_Float16)x;
  return c.u;
}
__device__ __forceinline__ u32 pk2(float a, float b) {
  union { fp16x2 h; u32 u; } c;
  c.h = __builtin_amdgcn_cvt_pkrtz(a, b);
  return c.u;
}
__device__ __forceinline__ void swap32(u32& a, u32& b) {
  asm volatile("v_permlane32_swap_b32 %0, %1" : "+v"(a), "+v"(b));
}
__device__ __forceinline__ void swap16(u32& a, u32& b) {
  asm volatile("v_permlane16_swap_b32 %0, %1" : "+v"(a), "+v"(b));
}
__device__ __forceinline__ void gload16(const u16* g, u16* l) {
  __builtin_amdgcn_global_load_lds(
      (const __attribute__((address_space(1))) void*)g,
      (__attribute__((address_space(3))) void*)l, 16, 0, 0);
}
__device__ __forceinline__ f32x4 MFMA(f16x8 a, f16x8 b, f32x4 c) {
  return __builtin_amdgcn_mfma_f32_16x16x32_f16(a, b, c, 0, 0, 0);
}
__device__ __forceinline__ f32x16 MFMA32(f16x8 a, f16x8 b, f32x16 c) {
  return __builtin_amdgcn_mfma_f32_32x32x16_f16(a, b, c, 0, 0, 0);
}

// ---------------- elementwise fp32 -> fp16 ----------------
__global__ void conv_f16(const float4* __restrict__ src, u16* __restrict__ d, int n4) {
  int i = blockIdx.x * 256 + threadIdx.x;
  if (i >= n4) return;
  float4 v = src[i];
  union { u16 u[4]; uint2 q; } H;
  H.u[0] = f2h(v.x); H.u[1] = f2h(v.y); H.u[2] = f2h(v.z); H.u[3] = f2h(v.w);
  *(uint2*)&d[(size_t)i * 4] = H.q;
}

// ---------------- transpose [K x N] fp32 -> [N x 2048] fp16 ----------------
__global__ void transpose_f16(const float* __restrict__ src, int K, int N,
                              u16* __restrict__ d, int rowOff) {
  __shared__ float t[32][33];
  int n0 = blockIdx.x * 32, k0 = blockIdx.y * 32;
  int tx = threadIdx.x, ty = threadIdx.y;
#pragma unroll
  for (int i = 0; i < 4; ++i)
    t[ty + 8 * i][tx] = src[(size_t)(k0 + ty + 8 * i) * N + n0 + tx];
  __syncthreads();
#pragma unroll
  for (int i = 0; i < 4; ++i) {
    int n = n0 + ty + 8 * i, k = k0 + tx;
    d[(size_t)(rowOff + n) * 2048 + k] = f2h(t[tx][ty + 8 * i]);
  }
}

// ---- QKV GEMM: 256x128 tile, 8 waves, 32x32x16 MFMA, 3-buffer counted,
//      ONE barrier/step, PERSISTENT 768 jobs on 512-block grid ----
__global__ __launch_bounds__(512) void gemm_qkv(
    const u16* __restrict__ A, const u16* __restrict__ B,
    u16* __restrict__ Qf, u16* __restrict__ Kf, u16* __restrict__ VT) {
  const int K = 2048;
  const int NS = K / 32;
  __shared__ u16 As[3][256 * 32];
  __shared__ u16 Bs[3][128 * 32];
  int tid = threadIdx.x;
  int l = tid & 63, w = tid >> 6;
  int l31 = l & 31, h5 = l >> 5;
  int wr = w >> 1, wc = w & 1;
  int r0 = tid >> 2;
  int ssrc = (((tid & 3) ^ ((r0 >> 1) & 3))) * 8;
  size_t half = (size_t)128 * K;
  int swz32 = (l31 >> 1) & 3;

  for (int job = blockIdx.x; job < 768; job += 512) {
    int lidx = (job & 7) * 96 + (job >> 3);
    int bx = lidx % 24, by = lidx / 24;
    int rowA = by * 256, colB = bx * 128;
    const u16* ga = A + (size_t)(rowA + r0) * K + ssrc;
    const u16* gb = B + (size_t)(colB + r0) * K + ssrc;
    f32x16 acc[2][2] = {};

    gload16(ga, &As[0][tid * 8]);
    gload16(ga + half, &As[0][4096 + tid * 8]);
    gload16(gb, &Bs[0][tid * 8]);
    gload16(ga + 32, &As[1][tid * 8]);
    gload16(ga + 32 + half, &As[1][4096 + tid * 8]);
    gload16(gb + 32, &Bs[1][tid * 8]);
    asm volatile("s_waitcnt vmcnt(3)" ::: "memory");
    __builtin_amdgcn_sched_barrier(0);
    __builtin_amdgcn_s_barrier();
    __builtin_amdgcn_sched_barrier(0);

    for (int t = 0; t < NS; ++t) {
      int cur = t % 3, nxt = (t + 2) % 3;
      bool pre = (t + 2 < NS);
      int kb2 = (t + 2) * 32;
      f16x8 af[2][2], bf[2][2];
#pragma unroll
      for (int i = 0; i < 2; ++i)
#pragma unroll
        for (int kh = 0; kh < 2; ++kh)
          af[i][kh] = *(const f16x8*)&As[cur][(wr * 64 + i * 32 + l31) * 32 +
                                             (((kh * 2 + h5) ^ swz32) * 8)];
#pragma unroll
      for (int j = 0; j < 2; ++j)
#pragma unroll
        for (int kh = 0; kh < 2; ++kh)
          bf[j][kh] = *(const f16x8*)&Bs[cur][(wc * 64 + j * 32 + l31) * 32 +
                                             (((kh * 2 + h5) ^ swz32) * 8)];
      if (pre) {
        gload16(ga + kb2, &As[nxt][tid * 8]);
        gload16(ga + kb2 + half, &As[nxt][4096 + tid * 8]);
        gload16(gb + kb2, &Bs[nxt][tid * 8]);
      }
      __builtin_amdgcn_s_setprio(1);
#pragma unroll
      for (int i = 0; i < 2; ++i)
#pragma unroll
        for (int j = 0; j < 2; ++j) {
          acc[i][j] = MFMA32(af[i][0], bf[j][0], acc[i][j]);
          acc[i][j] = MFMA32(af[i][1], bf[j][1], acc[i][j]);
        }
      __builtin_amdgcn_s_setprio(0);
      if (pre) {
        asm volatile("s_waitcnt vmcnt(3)" ::: "memory");
      } else {
        asm volatile("s_waitcnt vmcnt(0)" ::: "memory");
      }
      __builtin_amdgcn_sched_barrier(0);
      __builtin_amdgcn_s_barrier();
      __builtin_amdgcn_sched_barrier(0);
    }

    // epilogue: C/D layout 32x32 = col (l&31), row (reg&3)+8*(reg>>2)+4*(l>>5)
#pragma unroll
    for (int i = 0; i < 2; ++i) {
#pragma unroll
      for (int j = 0; j < 2; ++j) {
        int c = colB + wc * 64 + j * 32 + l31;
        if (c < 2048) {
#pragma unroll
          for (int g = 0; g < 4; ++g) {
            int row0 = rowA + wr * 64 + i * 32 + g * 8 + h5 * 4;
#pragma unroll
            for (int r = 0; r < 4; ++r)
              Qf[(size_t)(row0 + r) * 2048 + c] = f2h(acc[i][j][g * 4 + r]);
          }
        } else if (c < 2560) {
          int ck = c - 2048;
#pragma unroll
          for (int g = 0; g < 4; ++g) {
            int row0 = rowA + wr * 64 + i * 32 + g * 8 + h5 * 4;
#pragma unroll
            for (int r = 0; r < 4; ++r)
              Kf[(size_t)(row0 + r) * 512 + ck] = f2h(acc[i][j][g * 4 + r]);
          }
        } else {
          int cv = c - 2560, kvh = cv >> 7, d = cv & 127;
#pragma unroll
          for (int g = 0; g < 4; ++g) {
            int row0 = rowA + wr * 64 + i * 32 + g * 8 + h5 * 4;
            int b = row0 >> 11, t2 = row0 & 2047;
            union { u16 u[4]; uint2 q; } P;
#pragma unroll
            for (int r = 0; r < 4; ++r) P.u[r] = f2h(acc[i][j][g * 4 + r]);
            *(uint2*)&VT[((size_t)(b * 4 + kvh) * 128 + d) * 2048 + t2] = P.q;
          }
        }
      }
    }
    __builtin_amdgcn_s_barrier();
    __builtin_amdgcn_sched_barrier(0);
  }
}

// ---- out-proj GEMM: 256x128 tile, 8 waves, 32x32x16 MFMA, 3-buffer counted ----
__global__ __launch_bounds__(512) void gemm_out(
    const u16* __restrict__ A, const u16* __restrict__ B,
    float* __restrict__ Out, const float* __restrict__ bias) {
  const int K = 2048;
  const int NS = K / 32;
  __shared__ u16 As[3][256 * 32];
  __shared__ u16 Bs[3][128 * 32];
  int tid = threadIdx.x;
  int l = tid & 63, w = tid >> 6;
  int l31 = l & 31, h5 = l >> 5;
  int wr = w >> 1, wc = w & 1;
  int p = blockIdx.x;
  int lidx = (p & 7) * 64 + (p >> 3);
  int bx = lidx & 15, by = lidx >> 4;
  int rowA = by * 256, colB = bx * 128;
  int r0 = tid >> 2;
  int ssrc = (((tid & 3) ^ ((r0 >> 1) & 3))) * 8;
  const u16* ga = A + (size_t)(rowA + r0) * K + ssrc;
  const u16* gb = B + (size_t)(colB + r0) * K + ssrc;
  size_t half = (size_t)128 * K;
  f32x16 acc[2][2] = {};
  int swz32 = (l31 >> 1) & 3;

  gload16(ga, &As[0][tid * 8]);
  gload16(ga + half, &As[0][4096 + tid * 8]);
  gload16(gb, &Bs[0][tid * 8]);
  gload16(ga + 32, &As[1][tid * 8]);
  gload16(ga + 32 + half, &As[1][4096 + tid * 8]);
  gload16(gb + 32, &Bs[1][tid * 8]);
  asm volatile("s_waitcnt vmcnt(3)" ::: "memory");
  __builtin_amdgcn_sched_barrier(0);
  __builtin_amdgcn_s_barrier();
  __builtin_amdgcn_sched_barrier(0);

  for (int t = 0; t < NS; ++t) {
    int cur = t % 3, nxt = (t + 2) % 3;
    bool pre = (t + 2 < NS);
    int kb2 = (t + 2) * 32;
    f16x8 af[2][2], bf[2][2];
#pragma unroll
    for (int i = 0; i < 2; ++i)
#pragma unroll
      for (int kh = 0; kh < 2; ++kh)
        af[i][kh] = *(const f16x8*)&As[cur][(wr * 64 + i * 32 + l31) * 32 +
                                           (((kh * 2 + h5) ^ swz32) * 8)];
#pragma unroll
    for (int j = 0; j < 2; ++j)
#pragma unroll
      for (int kh = 0; kh < 2; ++kh)
        bf[j][kh] = *(const f16x8*)&Bs[cur][(wc * 64 + j * 32 + l31) * 32 +
                                           (((kh * 2 + h5) ^ swz32) * 8)];
    if (pre) {
      gload16(ga + kb2, &As[nxt][tid * 8]);
      gload16(ga + kb2 + half, &As[nxt][4096 + tid * 8]);
      gload16(gb + kb2, &Bs[nxt][tid * 8]);
    }
    __builtin_amdgcn_s_setprio(1);
#pragma unroll
    for (int i = 0; i < 2; ++i)
#pragma unroll
      for (int j = 0; j < 2; ++j) {
        acc[i][j] = MFMA32(af[i][0], bf[j][0], acc[i][j]);
        acc[i][j] = MFMA32(af[i][1], bf[j][1], acc[i][j]);
      }
    __builtin_amdgcn_s_setprio(0);
    if (pre) {
      asm volatile("s_waitcnt vmcnt(3)" ::: "memory");
    } else {
      asm volatile("s_waitcnt vmcnt(0)" ::: "memory");
    }
    __builtin_amdgcn_sched_barrier(0);
    __builtin_amdgcn_s_barrier();
    __builtin_amdgcn_sched_barrier(0);
  }

#pragma unroll
  for (int i = 0; i < 2; ++i) {
#pragma unroll
    for (int j = 0; j < 2; ++j) {
      int c = colB + wc * 64 + j * 32 + l31;
      float bb = bias[c];
#pragma unroll
      for (int g = 0; g < 4; ++g) {
        int row0 = rowA + wr * 64 + i * 32 + g * 8 + h5 * 4;
#pragma unroll
        for (int r = 0; r < 4; ++r)
          Out[(size_t)(row0 + r) * 2048 + c] = acc[i][j][g * 4 + r] + bb;
      }
    }
  }
}

// ---------------- flash attention v7 + XCD-chunked swizzle (unchanged) ----------------
__global__ __launch_bounds__(512) void attn_kernel(
    const u16* __restrict__ Qf, const u16* __restrict__ Kf,
    const u16* __restrict__ VT, u16* __restrict__ Ch) {
  __shared__ u16 Ks[2][64 * 128];
  __shared__ u16 Vs[2][128 * 64];

  int tid = threadIdx.x;
  int w = tid >> 6, l = tid & 63;
  int lr = l & 15, lg = l >> 4;

  int p = blockIdx.x;
  int bid = (p & 7) * 64 + (p >> 3);
  int pair = bid & 7;
  int hg = (bid >> 3) & 3;
  int kvh = (bid >> 5) & 3;
  int b = bid >> 7;
  int h = kvh * 4 + hg;

  const u16* Kb = Kf + (size_t)(b * 2048) * 512 + kvh * 128;
  const u16* Vb = VT + (size_t)((b * 4 + kvh) * 128) * 2048;

  auto STAGE_K = [&](int t, int bufi) {
    int kv0 = t * 64;
#pragma unroll
    for (int pp = 0; pp < 2; ++pp) {
      int o16 = pp * 512 + tid;
      int krow = o16 >> 4;
      int kslot = ((o16 & 15) ^ (krow & 7)) * 8;
      gload16(Kb + (size_t)(kv0 + krow) * 512 + kslot, &Ks[bufi][o16 * 8]);
    }
  };
  auto STAGE_V = [&](int t, int bufi) {
    int kv0 = t * 64;
#pragma unroll
    for (int pp = 0; pp < 2; ++pp) {
      int o16 = pp * 512 + tid;
      int vrow = o16 >> 3;
      int vslot = ((o16 & 7) ^ (vrow & 7)) * 8;
      gload16(Vb + (size_t)vrow * 2048 + kv0 + vslot, &Vs[bufi][o16 * 8]);
    }
  };

  for (int pass = 0; pass < 2; ++pass) {
    int tIdx = pass == 0 ? (15 - pair) : pair;
    int q0 = tIdx * 128;
    int qr0 = q0 + w * 16;
    int nt = q0 / 64 + 2;

    size_t qbase = (size_t)(b * 2048 + qr0 + lr) * 2048 + h * 128 + lg * 8;
    f16x8 qf[4];
#pragma unroll
    for (int d = 0; d < 4; ++d)
      qf[d] = *(const f16x8*)(Qf + qbase + d * 32);

    f32x4 o[8] = {};
    float mrun = -3e38f;
    float lp = 0.f;

    STAGE_K(0, 0);
    STAGE_V(0, 0);
    asm volatile("s_waitcnt vmcnt(0)" ::: "memory");
    __builtin_amdgcn_sched_barrier(0);
    __builtin_amdgcn_s_barrier();
    __builtin_amdgcn_sched_barrier(0);

    int cur = 0;
    for (int t = 0; t < nt; ++t) {
      int kv0 = t * 64;
      bool more = (t + 1 < nt);
      if (more) {
        STAGE_K(t + 1, cur ^ 1);
        STAGE_V(t + 1, cur ^ 1);
      }
      bool compute = (kv0 <= qr0 + 15);

      if (compute) {
        f32x4 s[4] = {};
        __builtin_amdgcn_s_setprio(1);
#pragma unroll
        for (int d = 0; d < 4; ++d) {
#pragma unroll
          for (int n = 0; n < 4; ++n) {
            int row = n * 16 + lr;
            int sl = ((d * 4 + lg) ^ (row & 7)) * 8;
            f16x8 kf = *(const f16x8*)&Ks[cur][row * 128 + sl];
            s[n] = MFMA(kf, qf[d], s[n]);
          }
        }
        __builtin_amdgcn_s_setprio(0);
        if (kv0 + 63 > qr0) {
#pragma unroll
          for (int n = 0; n < 4; ++n)
#pragma unroll
            for (int r = 0; r < 4; ++r)
              if (kv0 + n * 16 + lg * 4 + r > qr0 + lr) s[n][r] = -3e38f;
        }
        float m0 = fmaxf(fmaxf(s[0][0], s[0][1]), fmaxf(s[0][2], s[0][3]));
        float m1 = fmaxf(fmaxf(s[1][0], s[1][1]), fmaxf(s[1][2], s[1][3]));
        float m2 = fmaxf(fmaxf(s[2][0], s[2][1]), fmaxf(s[2][2], s[2][3]));
        float m3 = fmaxf(fmaxf(s[3][0], s[3][1]), fmaxf(s[3][2], s[3][3]));
        float rowmax = fmaxf(fmaxf(m0, m1), fmaxf(m2, m3));
        if (__any(rowmax > mrun + 8.f)) {
          float tm = rowmax;
          tm = fmaxf(tm, __shfl_xor(tm, 16));
          tm = fmaxf(tm, __shfl_xor(tm, 32));
          float mn = fmaxf(mrun, tm);
          float alpha = __builtin_amdgcn_exp2f((mrun - mn) * LOG2E);
          mrun = mn;
          lp *= alpha;
#pragma unroll
          for (int dt = 0; dt < 8; ++dt)
#pragma unroll
            for (int r = 0; r < 4; ++r) o[dt][r] *= alpha;
        }
        float mL = mrun * LOG2E;
        float pv[4][4];
#pragma unroll
        for (int n = 0; n < 4; ++n)
#pragma unroll
          for (int r = 0; r < 4; ++r) {
            pv[n][r] = __builtin_amdgcn_exp2f(fmaf(s[n][r], LOG2E, -mL));
            lp += pv[n][r];
          }
        u32 A0[4], A1[4];
#pragma unroll
        for (int n = 0; n < 4; ++n) {
          A0[n] = pk2(pv[n][0], pv[n][1]);
          A1[n] = pk2(pv[n][2], pv[n][3]);
        }
        swap32(A0[0], A0[2]); swap32(A0[1], A0[3]);
        swap32(A1[0], A1[2]); swap32(A1[1], A1[3]);
        swap16(A0[0], A0[2]); swap16(A0[1], A0[3]);
        swap16(A1[0], A1[2]); swap16(A1[1], A1[3]);
        swap32(A0[0], A0[1]); swap32(A0[2], A0[3]);
        swap32(A1[0], A1[1]); swap32(A1[2], A1[3]);
        union { u32 w4[4]; f16x8 v; } P0, P1;
        P0.w4[0] = A0[0]; P0.w4[1] = A1[0]; P0.w4[2] = A0[2]; P0.w4[3] = A1[2];
        P1.w4[0] = A0[1]; P1.w4[1] = A1[1]; P1.w4[2] = A0[3]; P1.w4[3] = A1[3];
        __builtin_amdgcn_s_setprio(1);
#pragma unroll
        for (int n2 = 0; n2 < 2; ++n2) {
          f16x8 pf = n2 ? P1.v : P0.v;
#pragma unroll
          for (int dt = 0; dt < 8; ++dt) {
            int d = dt * 16 + lr;
            f16x8 vf = *(const f16x8*)&Vs[cur][d * 64 + (((n2 * 4 + lg) ^ (lr & 7)) * 8)];
            o[dt] = MFMA(vf, pf, o[dt]);
          }
        }
        __builtin_amdgcn_s_setprio(0);
      }
      asm volatile("s_waitcnt vmcnt(0) lgkmcnt(0)" ::: "memory");
      __builtin_amdgcn_sched_barrier(0);
      __builtin_amdgcn_s_barrier();
      __builtin_amdgcn_sched_barrier(0);
      cur ^= 1;
    }
    lp += __shfl_xor(lp, 16);
    lp += __shfl_xor(lp, 32);
    float inv = 1.0f / lp;
    size_t orow = (size_t)(b * 2048 + qr0 + lr) * 2048 + h * 128 + lg * 4;
#pragma unroll
    for (int dt = 0; dt < 8; ++dt) {
      uint2 pkt;
      pkt.x = pk2(o[dt][0] * inv, o[dt][1] * inv);
      pkt.y = pk2(o[dt][2] * inv, o[dt][3] * inv);
      *(uint2*)&Ch[orow + dt * 16] = pkt;
    }
  }
}

extern "C" void kernel_launch(void* const* d_in, const int* in_sizes, int n_in,
                              void* d_out, int out_size, void* d_ws, size_t ws_size,
                              hipStream_t stream) {
  const float* X  = (const float*)d_in[0];
  const float* qw = (const float*)d_in[1];
  const float* kw = (const float*)d_in[2];
  const float* vw = (const float*)d_in[3];
  const float* ow = (const float*)d_in[4];
  const float* ob = (const float*)d_in[5];
  float* Out = (float*)d_out;

  char* ws = (char*)d_ws;
  size_t off = 0;
  auto alloc = [&](size_t bytes) -> void* {
    void* p = ws + off;
    off += (bytes + 255) & ~(size_t)255;
    return p;
  };
  const size_t MK = (size_t)8192 * 2048;
  u16* Xf = (u16*)alloc(MK * 2);
  u16* Bt = (u16*)alloc((size_t)3072 * 2048 * 2);
  u16* OW = (u16*)alloc((size_t)2048 * 2048 * 2);
  u16* Qf = (u16*)alloc(MK * 2);
  u16* Kf = (u16*)alloc((size_t)8192 * 512 * 2);
  u16* VT = (u16*)alloc((size_t)8192 * 512 * 2);
  u16* Ch = (u16*)alloc(MK * 2);

  conv_f16<<<dim3(16384), dim3(256), 0, stream>>>((const float4*)X, Xf, (int)(MK / 4));
  dim3 tb(32, 8);
  transpose_f16<<<dim3(64, 64), tb, 0, stream>>>(qw, 2048, 2048, Bt, 0);
  transpose_f16<<<dim3(16, 64), tb, 0, stream>>>(kw, 2048, 512, Bt, 2048);
  transpose_f16<<<dim3(16, 64), tb, 0, stream>>>(vw, 2048, 512, Bt, 2560);
  transpose_f16<<<dim3(64, 64), tb, 0, stream>>>(ow, 2048, 2048, OW, 0);
  gemm_qkv<<<dim3(512), dim3(512), 0, stream>>>(Xf, Bt, Qf, Kf, VT);
  attn_kernel<<<dim3(512), dim3(512), 0, stream>>>(Qf, Kf, VT, Ch);
  gemm_out<<<dim3(512), dim3(512), 0, stream>>>(Ch, OW, Out, ob);
}

// Round 21
// 333.288 us; speedup vs baseline: 1.0616x; 1.0616x over previous
//
#include <hip/hip_runtime.h>

typedef unsigned short u16;
typedef unsigned int   u32;
typedef __attribute__((ext_vector_type(8))) _Float16 f16x8;
typedef __attribute__((ext_vector_type(2))) __fp16   fp16x2;
typedef __attribute__((ext_vector_type(4))) float    f32x4;

#define LOG2E 1.44269504088896340f

__device__ __forceinline__ u16 f2h(float x) {
  union { _Float16 h; u16 u; } c;
  c.h = (_Float16)x;
  return c.u;
}
__device__ __forceinline__ u32 pk2(float a, float b) {
  union { fp16x2 h; u32 u; } c;
  c.h = __builtin_amdgcn_cvt_pkrtz(a, b);
  return c.u;
}
__device__ __forceinline__ void swap32(u32& a, u32& b) {
  asm volatile("v_permlane32_swap_b32 %0, %1" : "+v"(a), "+v"(b));
}
__device__ __forceinline__ void swap16(u32& a, u32& b) {
  asm volatile("v_permlane16_swap_b32 %0, %1" : "+v"(a), "+v"(b));
}
__device__ __forceinline__ void gload16(const u16* g, u16* l) {
  __builtin_amdgcn_global_load_lds(
      (const __attribute__((address_space(1))) void*)g,
      (__attribute__((address_space(3))) void*)l, 16, 0, 0);
}
__device__ __forceinline__ f32x4 MFMA(f16x8 a, f16x8 b, f32x4 c) {
  return __builtin_amdgcn_mfma_f32_16x16x32_f16(a, b, c, 0, 0, 0);
}

// ---------------- elementwise fp32 -> fp16 ----------------
__global__ void conv_f16(const float4* __restrict__ src, u16* __restrict__ d, int n4) {
  int i = blockIdx.x * 256 + threadIdx.x;
  if (i >= n4) return;
  float4 v = src[i];
  union { u16 u[4]; uint2 q; } H;
  H.u[0] = f2h(v.x); H.u[1] = f2h(v.y); H.u[2] = f2h(v.z); H.u[3] = f2h(v.w);
  *(uint2*)&d[(size_t)i * 4] = H.q;
}

// ---------------- transpose [K x N] fp32 -> [N x 2048] fp16 ----------------
__global__ void transpose_f16(const float* __restrict__ src, int K, int N,
                              u16* __restrict__ d, int rowOff) {
  __shared__ float t[32][33];
  int n0 = blockIdx.x * 32, k0 = blockIdx.y * 32;
  int tx = threadIdx.x, ty = threadIdx.y;
#pragma unroll
  for (int i = 0; i < 4; ++i)
    t[ty + 8 * i][tx] = src[(size_t)(k0 + ty + 8 * i) * N + n0 + tx];
  __syncthreads();
#pragma unroll
  for (int i = 0; i < 4; ++i) {
    int n = n0 + ty + 8 * i, k = k0 + tx;
    d[(size_t)(rowOff + n) * 2048 + k] = f2h(t[tx][ty + 8 * i]);
  }
}

// ---- QKV GEMM: 256x128 tile, 8 waves, 3-buffer counted, ONE barrier/step,
//      PERSISTENT blocks: 768 jobs on 512-block grid (3 jobs/CU balanced) ----
__global__ __launch_bounds__(512) void gemm_qkv(
    const u16* __restrict__ A, const u16* __restrict__ B,
    u16* __restrict__ Qf, u16* __restrict__ Kf, u16* __restrict__ VT) {
  const int K = 2048;
  const int NS = K / 32;
  __shared__ u16 As[3][256 * 32];
  __shared__ u16 Bs[3][128 * 32];
  int tid = threadIdx.x;
  int l = tid & 63, w = tid >> 6;
  int lr = l & 15, lg = l >> 4;
  int wr = w >> 1, wc = w & 1;
  int r0 = tid >> 2;
  int ssrc = (((tid & 3) ^ ((r0 >> 1) & 3))) * 8;
  size_t half = (size_t)128 * K;
  int swz = (lr >> 1) & 3;
  int aoff = (wr * 64 + lr) * 32 + (lg ^ swz) * 8;
  int boff = (wc * 64 + lr) * 32 + (lg ^ swz) * 8;

  for (int job = blockIdx.x; job < 768; job += 512) {
    // XCD-chunked logical index (job ≡ blockIdx mod 8 keeps XCD locality)
    int lidx = (job & 7) * 96 + (job >> 3);
    int bx = lidx % 24, by = lidx / 24;
    int rowA = by * 256, colB = bx * 128;
    const u16* ga = A + (size_t)(rowA + r0) * K + ssrc;
    const u16* gb = B + (size_t)(colB + r0) * K + ssrc;
    f32x4 acc[4][4] = {};

    gload16(ga, &As[0][tid * 8]);
    gload16(ga + half, &As[0][4096 + tid * 8]);
    gload16(gb, &Bs[0][tid * 8]);
    gload16(ga + 32, &As[1][tid * 8]);
    gload16(ga + 32 + half, &As[1][4096 + tid * 8]);
    gload16(gb + 32, &Bs[1][tid * 8]);
    asm volatile("s_waitcnt vmcnt(3)" ::: "memory");
    __builtin_amdgcn_sched_barrier(0);
    __builtin_amdgcn_s_barrier();
    __builtin_amdgcn_sched_barrier(0);

    for (int t = 0; t < NS; ++t) {
      int cur = t % 3, nxt = (t + 2) % 3;
      bool pre = (t + 2 < NS);
      int kb2 = (t + 2) * 32;
      f16x8 ah[4], bh[4];
#pragma unroll
      for (int i = 0; i < 4; ++i)
        ah[i] = *(const f16x8*)&As[cur][aoff + i * 512];
#pragma unroll
      for (int j = 0; j < 4; ++j)
        bh[j] = *(const f16x8*)&Bs[cur][boff + j * 512];
      if (pre) {
        gload16(ga + kb2, &As[nxt][tid * 8]);
        gload16(ga + kb2 + half, &As[nxt][4096 + tid * 8]);
        gload16(gb + kb2, &Bs[nxt][tid * 8]);
      }
      __builtin_amdgcn_s_setprio(1);
#pragma unroll
      for (int i = 0; i < 4; ++i)
#pragma unroll
        for (int j = 0; j < 4; ++j)
          acc[i][j] = MFMA(ah[i], bh[j], acc[i][j]);
      __builtin_amdgcn_s_setprio(0);
      if (pre) {
        asm volatile("s_waitcnt vmcnt(3)" ::: "memory");
      } else {
        asm volatile("s_waitcnt vmcnt(0)" ::: "memory");
      }
      __builtin_amdgcn_sched_barrier(0);
      __builtin_amdgcn_s_barrier();
      __builtin_amdgcn_sched_barrier(0);
    }

#pragma unroll
    for (int i = 0; i < 4; ++i) {
      int row0 = rowA + wr * 64 + i * 16 + lg * 4;
#pragma unroll
      for (int j = 0; j < 4; ++j) {
        int c = colB + wc * 64 + j * 16 + lr;
        f32x4 v = acc[i][j];
        if (c < 2048) {
#pragma unroll
          for (int r = 0; r < 4; ++r)
            Qf[(size_t)(row0 + r) * 2048 + c] = f2h(v[r]);
        } else if (c < 2560) {
          int ck = c - 2048;
#pragma unroll
          for (int r = 0; r < 4; ++r)
            Kf[(size_t)(row0 + r) * 512 + ck] = f2h(v[r]);
        } else {
          int cv = c - 2560, kvh = cv >> 7, d = cv & 127;
          int b = row0 >> 11, t2 = row0 & 2047;
          union { u16 u[4]; uint2 q; } P;
#pragma unroll
          for (int r = 0; r < 4; ++r) P.u[r] = f2h(v[r]);
          *(uint2*)&VT[((size_t)(b * 4 + kvh) * 128 + d) * 2048 + t2] = P.q;
        }
      }
    }
    // make LDS reuse across jobs safe: all waves done with epilogue reads
    __builtin_amdgcn_s_barrier();
    __builtin_amdgcn_sched_barrier(0);
  }
}

// ---- out-proj GEMM: 256x128 tile, 8 waves, 3-buffer counted, ONE barrier/step ----
__global__ __launch_bounds__(512) void gemm_out(
    const u16* __restrict__ A, const u16* __restrict__ B,
    float* __restrict__ Out, const float* __restrict__ bias) {
  const int K = 2048;
  const int NS = K / 32;
  __shared__ u16 As[3][256 * 32];
  __shared__ u16 Bs[3][128 * 32];
  int tid = threadIdx.x;
  int l = tid & 63, w = tid >> 6;
  int lr = l & 15, lg = l >> 4;
  int wr = w >> 1, wc = w & 1;
  int p = blockIdx.x;
  int lidx = (p & 7) * 64 + (p >> 3);
  int bx = lidx & 15, by = lidx >> 4;
  int rowA = by * 256, colB = bx * 128;
  int r0 = tid >> 2;
  int ssrc = (((tid & 3) ^ ((r0 >> 1) & 3))) * 8;
  const u16* ga = A + (size_t)(rowA + r0) * K + ssrc;
  const u16* gb = B + (size_t)(colB + r0) * K + ssrc;
  size_t half = (size_t)128 * K;
  f32x4 acc[4][4] = {};
  int swz = (lr >> 1) & 3;
  int aoff = (wr * 64 + lr) * 32 + (lg ^ swz) * 8;
  int boff = (wc * 64 + lr) * 32 + (lg ^ swz) * 8;

  gload16(ga, &As[0][tid * 8]);
  gload16(ga + half, &As[0][4096 + tid * 8]);
  gload16(gb, &Bs[0][tid * 8]);
  gload16(ga + 32, &As[1][tid * 8]);
  gload16(ga + 32 + half, &As[1][4096 + tid * 8]);
  gload16(gb + 32, &Bs[1][tid * 8]);
  asm volatile("s_waitcnt vmcnt(3)" ::: "memory");
  __builtin_amdgcn_sched_barrier(0);
  __builtin_amdgcn_s_barrier();
  __builtin_amdgcn_sched_barrier(0);

  for (int t = 0; t < NS; ++t) {
    int cur = t % 3, nxt = (t + 2) % 3;
    bool pre = (t + 2 < NS);
    int kb2 = (t + 2) * 32;
    f16x8 ah[4], bh[4];
#pragma unroll
    for (int i = 0; i < 4; ++i)
      ah[i] = *(const f16x8*)&As[cur][aoff + i * 512];
#pragma unroll
    for (int j = 0; j < 4; ++j)
      bh[j] = *(const f16x8*)&Bs[cur][boff + j * 512];
    if (pre) {
      gload16(ga + kb2, &As[nxt][tid * 8]);
      gload16(ga + kb2 + half, &As[nxt][4096 + tid * 8]);
      gload16(gb + kb2, &Bs[nxt][tid * 8]);
    }
    __builtin_amdgcn_s_setprio(1);
#pragma unroll
    for (int i = 0; i < 4; ++i)
#pragma unroll
      for (int j = 0; j < 4; ++j)
        acc[i][j] = MFMA(ah[i], bh[j], acc[i][j]);
    __builtin_amdgcn_s_setprio(0);
    if (pre) {
      asm volatile("s_waitcnt vmcnt(3)" ::: "memory");
    } else {
      asm volatile("s_waitcnt vmcnt(0)" ::: "memory");
    }
    __builtin_amdgcn_sched_barrier(0);
    __builtin_amdgcn_s_barrier();
    __builtin_amdgcn_sched_barrier(0);
  }

#pragma unroll
  for (int i = 0; i < 4; ++i) {
    int row0 = rowA + wr * 64 + i * 16 + lg * 4;
#pragma unroll
    for (int j = 0; j < 4; ++j) {
      int c = colB + wc * 64 + j * 16 + lr;
      float bb = bias[c];
#pragma unroll
      for (int r = 0; r < 4; ++r)
        Out[(size_t)(row0 + r) * 2048 + c] = acc[i][j][r] + bb;
    }
  }
}

// ---------------- flash attention v7 + XCD-chunked swizzle ----------------
__global__ __launch_bounds__(512) void attn_kernel(
    const u16* __restrict__ Qf, const u16* __restrict__ Kf,
    const u16* __restrict__ VT, u16* __restrict__ Ch) {
  __shared__ u16 Ks[2][64 * 128];
  __shared__ u16 Vs[2][128 * 64];

  int tid = threadIdx.x;
  int w = tid >> 6, l = tid & 63;
  int lr = l & 15, lg = l >> 4;

  int p = blockIdx.x;
  int bid = (p & 7) * 64 + (p >> 3);
  int pair = bid & 7;
  int hg = (bid >> 3) & 3;
  int kvh = (bid >> 5) & 3;
  int b = bid >> 7;
  int h = kvh * 4 + hg;

  const u16* Kb = Kf + (size_t)(b * 2048) * 512 + kvh * 128;
  const u16* Vb = VT + (size_t)((b * 4 + kvh) * 128) * 2048;

  auto STAGE_K = [&](int t, int bufi) {
    int kv0 = t * 64;
#pragma unroll
    for (int pp = 0; pp < 2; ++pp) {
      int o16 = pp * 512 + tid;
      int krow = o16 >> 4;
      int kslot = ((o16 & 15) ^ (krow & 7)) * 8;
      gload16(Kb + (size_t)(kv0 + krow) * 512 + kslot, &Ks[bufi][o16 * 8]);
    }
  };
  auto STAGE_V = [&](int t, int bufi) {
    int kv0 = t * 64;
#pragma unroll
    for (int pp = 0; pp < 2; ++pp) {
      int o16 = pp * 512 + tid;
      int vrow = o16 >> 3;
      int vslot = ((o16 & 7) ^ (vrow & 7)) * 8;
      gload16(Vb + (size_t)vrow * 2048 + kv0 + vslot, &Vs[bufi][o16 * 8]);
    }
  };

  for (int pass = 0; pass < 2; ++pass) {
    int tIdx = pass == 0 ? (15 - pair) : pair;
    int q0 = tIdx * 128;
    int qr0 = q0 + w * 16;
    int nt = q0 / 64 + 2;

    size_t qbase = (size_t)(b * 2048 + qr0 + lr) * 2048 + h * 128 + lg * 8;
    f16x8 qf[4];
#pragma unroll
    for (int d = 0; d < 4; ++d)
      qf[d] = *(const f16x8*)(Qf + qbase + d * 32);

    f32x4 o[8] = {};
    float mrun = -3e38f;
    float lp = 0.f;

    STAGE_K(0, 0);
    STAGE_V(0, 0);
    asm volatile("s_waitcnt vmcnt(0)" ::: "memory");
    __builtin_amdgcn_sched_barrier(0);
    __builtin_amdgcn_s_barrier();
    __builtin_amdgcn_sched_barrier(0);

    int cur = 0;
    for (int t = 0; t < nt; ++t) {
      int kv0 = t * 64;
      bool more = (t + 1 < nt);
      if (more) {
        STAGE_K(t + 1, cur ^ 1);
        STAGE_V(t + 1, cur ^ 1);
      }
      bool compute = (kv0 <= qr0 + 15);

      if (compute) {
        f32x4 s[4] = {};
        __builtin_amdgcn_s_setprio(1);
#pragma unroll
        for (int d = 0; d < 4; ++d) {
#pragma unroll
          for (int n = 0; n < 4; ++n) {
            int row = n * 16 + lr;
            int sl = ((d * 4 + lg) ^ (row & 7)) * 8;
            f16x8 kf = *(const f16x8*)&Ks[cur][row * 128 + sl];
            s[n] = MFMA(kf, qf[d], s[n]);
          }
        }
        __builtin_amdgcn_s_setprio(0);
        if (kv0 + 63 > qr0) {
#pragma unroll
          for (int n = 0; n < 4; ++n)
#pragma unroll
            for (int r = 0; r < 4; ++r)
              if (kv0 + n * 16 + lg * 4 + r > qr0 + lr) s[n][r] = -3e38f;
        }
        float m0 = fmaxf(fmaxf(s[0][0], s[0][1]), fmaxf(s[0][2], s[0][3]));
        float m1 = fmaxf(fmaxf(s[1][0], s[1][1]), fmaxf(s[1][2], s[1][3]));
        float m2 = fmaxf(fmaxf(s[2][0], s[2][1]), fmaxf(s[2][2], s[2][3]));
        float m3 = fmaxf(fmaxf(s[3][0], s[3][1]), fmaxf(s[3][2], s[3][3]));
        float rowmax = fmaxf(fmaxf(m0, m1), fmaxf(m2, m3));
        if (__any(rowmax > mrun + 8.f)) {
          float tm = rowmax;
          tm = fmaxf(tm, __shfl_xor(tm, 16));
          tm = fmaxf(tm, __shfl_xor(tm, 32));
          float mn = fmaxf(mrun, tm);
          float alpha = __builtin_amdgcn_exp2f((mrun - mn) * LOG2E);
          mrun = mn;
          lp *= alpha;
#pragma unroll
          for (int dt = 0; dt < 8; ++dt)
#pragma unroll
            for (int r = 0; r < 4; ++r) o[dt][r] *= alpha;
        }
        float mL = mrun * LOG2E;
        float pv[4][4];
#pragma unroll
        for (int n = 0; n < 4; ++n)
#pragma unroll
          for (int r = 0; r < 4; ++r) {
            pv[n][r] = __builtin_amdgcn_exp2f(fmaf(s[n][r], LOG2E, -mL));
            lp += pv[n][r];
          }
        u32 A0[4], A1[4];
#pragma unroll
        for (int n = 0; n < 4; ++n) {
          A0[n] = pk2(pv[n][0], pv[n][1]);
          A1[n] = pk2(pv[n][2], pv[n][3]);
        }
        swap32(A0[0], A0[2]); swap32(A0[1], A0[3]);
        swap32(A1[0], A1[2]); swap32(A1[1], A1[3]);
        swap16(A0[0], A0[2]); swap16(A0[1], A0[3]);
        swap16(A1[0], A1[2]); swap16(A1[1], A1[3]);
        swap32(A0[0], A0[1]); swap32(A0[2], A0[3]);
        swap32(A1[0], A1[1]); swap32(A1[2], A1[3]);
        union { u32 w4[4]; f16x8 v; } P0, P1;
        P0.w4[0] = A0[0]; P0.w4[1] = A1[0]; P0.w4[2] = A0[2]; P0.w4[3] = A1[2];
        P1.w4[0] = A0[1]; P1.w4[1] = A1[1]; P1.w4[2] = A0[3]; P1.w4[3] = A1[3];
        __builtin_amdgcn_s_setprio(1);
#pragma unroll
        for (int n2 = 0; n2 < 2; ++n2) {
          f16x8 pf = n2 ? P1.v : P0.v;
#pragma unroll
          for (int dt = 0; dt < 8; ++dt) {
            int d = dt * 16 + lr;
            f16x8 vf = *(const f16x8*)&Vs[cur][d * 64 + (((n2 * 4 + lg) ^ (lr & 7)) * 8)];
            o[dt] = MFMA(vf, pf, o[dt]);
          }
        }
        __builtin_amdgcn_s_setprio(0);
      }
      asm volatile("s_waitcnt vmcnt(0) lgkmcnt(0)" ::: "memory");
      __builtin_amdgcn_sched_barrier(0);
      __builtin_amdgcn_s_barrier();
      __builtin_amdgcn_sched_barrier(0);
      cur ^= 1;
    }
    lp += __shfl_xor(lp, 16);
    lp += __shfl_xor(lp, 32);
    float inv = 1.0f / lp;
    size_t orow = (size_t)(b * 2048 + qr0 + lr) * 2048 + h * 128 + lg * 4;
#pragma unroll
    for (int dt = 0; dt < 8; ++dt) {
      uint2 pkt;
      pkt.x = pk2(o[dt][0] * inv, o[dt][1] * inv);
      pkt.y = pk2(o[dt][2] * inv, o[dt][3] * inv);
      *(uint2*)&Ch[orow + dt * 16] = pkt;
    }
  }
}

extern "C" void kernel_launch(void* const* d_in, const int* in_sizes, int n_in,
                              void* d_out, int out_size, void* d_ws, size_t ws_size,
                              hipStream_t stream) {
  const float* X  = (const float*)d_in[0];
  const float* qw = (const float*)d_in[1];
  const float* kw = (const float*)d_in[2];
  const float* vw = (const float*)d_in[3];
  const float* ow = (const float*)d_in[4];
  const float* ob = (const float*)d_in[5];
  float* Out = (float*)d_out;

  char* ws = (char*)d_ws;
  size_t off = 0;
  auto alloc = [&](size_t bytes) -> void* {
    void* p = ws + off;
    off += (bytes + 255) & ~(size_t)255;
    return p;
  };
  const size_t MK = (size_t)8192 * 2048;
  u16* Xf = (u16*)alloc(MK * 2);
  u16* Bt = (u16*)alloc((size_t)3072 * 2048 * 2);
  u16* OW = (u16*)alloc((size_t)2048 * 2048 * 2);
  u16* Qf = (u16*)alloc(MK * 2);
  u16* Kf = (u16*)alloc((size_t)8192 * 512 * 2);
  u16* VT = (u16*)alloc((size_t)8192 * 512 * 2);
  u16* Ch = (u16*)alloc(MK * 2);

  conv_f16<<<dim3(16384), dim3(256), 0, stream>>>((const float4*)X, Xf, (int)(MK / 4));
  dim3 tb(32, 8);
  transpose_f16<<<dim3(64, 64), tb, 0, stream>>>(qw, 2048, 2048, Bt, 0);
  transpose_f16<<<dim3(16, 64), tb, 0, stream>>>(kw, 2048, 512, Bt, 2048);
  transpose_f16<<<dim3(16, 64), tb, 0, stream>>>(vw, 2048, 512, Bt, 2560);
  transpose_f16<<<dim3(64, 64), tb, 0, stream>>>(ow, 2048, 2048, OW, 0);
  gemm_qkv<<<dim3(512), dim3(512), 0, stream>>>(Xf, Bt, Qf, Kf, VT);
  attn_kernel<<<dim3(512), dim3(512), 0, stream>>>(Qf, Kf, VT, Ch);
  gemm_out<<<dim3(512), dim3(512), 0, stream>>>(Ch, OW, Out, ob);
}

// Round 22
// 325.664 us; speedup vs baseline: 1.0865x; 1.0234x over previous
//
#include <hip/hip_runtime.h>

typedef unsigned short u16;
typedef unsigned int   u32;
typedef __attribute__((ext_vector_type(8))) _Float16 f16x8;
typedef __attribute__((ext_vector_type(2))) __fp16   fp16x2;
typedef __attribute__((ext_vector_type(4))) float    f32x4;

#define LOG2E 1.44269504088896340f

__device__ __forceinline__ u16 f2h(float x) {
  union { _Float16 h; u16 u; } c;
  c.h = (_Float16)x;
  return c.u;
}
__device__ __forceinline__ u32 pk2(float a, float b) {
  union { fp16x2 h; u32 u; } c;
  c.h = __builtin_amdgcn_cvt_pkrtz(a, b);
  return c.u;
}
__device__ __forceinline__ void swap32(u32& a, u32& b) {
  asm volatile("v_permlane32_swap_b32 %0, %1" : "+v"(a), "+v"(b));
}
__device__ __forceinline__ void swap16(u32& a, u32& b) {
  asm volatile("v_permlane16_swap_b32 %0, %1" : "+v"(a), "+v"(b));
}
__device__ __forceinline__ void gload16(const u16* g, u16* l) {
  __builtin_amdgcn_global_load_lds(
      (const __attribute__((address_space(1))) void*)g,
      (__attribute__((address_space(3))) void*)l, 16, 0, 0);
}
__device__ __forceinline__ f32x4 MFMA(f16x8 a, f16x8 b, f32x4 c) {
  return __builtin_amdgcn_mfma_f32_16x16x32_f16(a, b, c, 0, 0, 0);
}

// ---------------- elementwise fp32 -> fp16 ----------------
__global__ void conv_f16(const float4* __restrict__ src, u16* __restrict__ d, int n4) {
  int i = blockIdx.x * 256 + threadIdx.x;
  if (i >= n4) return;
  float4 v = src[i];
  union { u16 u[4]; uint2 q; } H;
  H.u[0] = f2h(v.x); H.u[1] = f2h(v.y); H.u[2] = f2h(v.z); H.u[3] = f2h(v.w);
  *(uint2*)&d[(size_t)i * 4] = H.q;
}

// ---------------- transpose [K x N] fp32 -> [N x 2048] fp16 ----------------
__global__ void transpose_f16(const float* __restrict__ src, int K, int N,
                              u16* __restrict__ d, int rowOff) {
  __shared__ float t[32][33];
  int n0 = blockIdx.x * 32, k0 = blockIdx.y * 32;
  int tx = threadIdx.x, ty = threadIdx.y;
#pragma unroll
  for (int i = 0; i < 4; ++i)
    t[ty + 8 * i][tx] = src[(size_t)(k0 + ty + 8 * i) * N + n0 + tx];
  __syncthreads();
#pragma unroll
  for (int i = 0; i < 4; ++i) {
    int n = n0 + ty + 8 * i, k = k0 + tx;
    d[(size_t)(rowOff + n) * 2048 + k] = f2h(t[tx][ty + 8 * i]);
  }
}

// ---- QKV GEMM: r21 proven state (256x128, 3-buf counted, persistent 768-on-512) ----
__global__ __launch_bounds__(512) void gemm_qkv(
    const u16* __restrict__ A, const u16* __restrict__ B,
    u16* __restrict__ Qf, u16* __restrict__ Kf, u16* __restrict__ VT) {
  const int K = 2048;
  const int NS = K / 32;
  __shared__ u16 As[3][256 * 32];
  __shared__ u16 Bs[3][128 * 32];
  int tid = threadIdx.x;
  int l = tid & 63, w = tid >> 6;
  int lr = l & 15, lg = l >> 4;
  int wr = w >> 1, wc = w & 1;
  int r0 = tid >> 2;
  int ssrc = (((tid & 3) ^ ((r0 >> 1) & 3))) * 8;
  size_t half = (size_t)128 * K;
  int swz = (lr >> 1) & 3;
  int aoff = (wr * 64 + lr) * 32 + (lg ^ swz) * 8;
  int boff = (wc * 64 + lr) * 32 + (lg ^ swz) * 8;

  for (int job = blockIdx.x; job < 768; job += 512) {
    int lidx = (job & 7) * 96 + (job >> 3);
    int bx = lidx % 24, by = lidx / 24;
    int rowA = by * 256, colB = bx * 128;
    const u16* ga = A + (size_t)(rowA + r0) * K + ssrc;
    const u16* gb = B + (size_t)(colB + r0) * K + ssrc;
    f32x4 acc[4][4] = {};

    gload16(ga, &As[0][tid * 8]);
    gload16(ga + half, &As[0][4096 + tid * 8]);
    gload16(gb, &Bs[0][tid * 8]);
    gload16(ga + 32, &As[1][tid * 8]);
    gload16(ga + 32 + half, &As[1][4096 + tid * 8]);
    gload16(gb + 32, &Bs[1][tid * 8]);
    asm volatile("s_waitcnt vmcnt(3)" ::: "memory");
    __builtin_amdgcn_sched_barrier(0);
    __builtin_amdgcn_s_barrier();
    __builtin_amdgcn_sched_barrier(0);

    for (int t = 0; t < NS; ++t) {
      int cur = t % 3, nxt = (t + 2) % 3;
      bool pre = (t + 2 < NS);
      int kb2 = (t + 2) * 32;
      f16x8 ah[4], bh[4];
#pragma unroll
      for (int i = 0; i < 4; ++i)
        ah[i] = *(const f16x8*)&As[cur][aoff + i * 512];
#pragma unroll
      for (int j = 0; j < 4; ++j)
        bh[j] = *(const f16x8*)&Bs[cur][boff + j * 512];
      if (pre) {
        gload16(ga + kb2, &As[nxt][tid * 8]);
        gload16(ga + kb2 + half, &As[nxt][4096 + tid * 8]);
        gload16(gb + kb2, &Bs[nxt][tid * 8]);
      }
      __builtin_amdgcn_s_setprio(1);
#pragma unroll
      for (int i = 0; i < 4; ++i)
#pragma unroll
        for (int j = 0; j < 4; ++j)
          acc[i][j] = MFMA(ah[i], bh[j], acc[i][j]);
      __builtin_amdgcn_s_setprio(0);
      if (pre) {
        asm volatile("s_waitcnt vmcnt(3)" ::: "memory");
      } else {
        asm volatile("s_waitcnt vmcnt(0)" ::: "memory");
      }
      __builtin_amdgcn_sched_barrier(0);
      __builtin_amdgcn_s_barrier();
      __builtin_amdgcn_sched_barrier(0);
    }

#pragma unroll
    for (int i = 0; i < 4; ++i) {
      int row0 = rowA + wr * 64 + i * 16 + lg * 4;
#pragma unroll
      for (int j = 0; j < 4; ++j) {
        int c = colB + wc * 64 + j * 16 + lr;
        f32x4 v = acc[i][j];
        if (c < 2048) {
#pragma unroll
          for (int r = 0; r < 4; ++r)
            Qf[(size_t)(row0 + r) * 2048 + c] = f2h(v[r]);
        } else if (c < 2560) {
          int ck = c - 2048;
#pragma unroll
          for (int r = 0; r < 4; ++r)
            Kf[(size_t)(row0 + r) * 512 + ck] = f2h(v[r]);
        } else {
          int cv = c - 2560, kvh = cv >> 7, d = cv & 127;
          int b = row0 >> 11, t2 = row0 & 2047;
          union { u16 u[4]; uint2 q; } P;
#pragma unroll
          for (int r = 0; r < 4; ++r) P.u[r] = f2h(v[r]);
          *(uint2*)&VT[((size_t)(b * 4 + kvh) * 128 + d) * 2048 + t2] = P.q;
        }
      }
    }
    __builtin_amdgcn_s_barrier();
    __builtin_amdgcn_sched_barrier(0);
  }
}

// ---- out-proj GEMM v2: 256x256 tile, BK=64, 8 waves (2Mx4N, 128x64/wave),
//      4-phase deep pipeline, 128KB LDS (1 block/CU), 256 blocks = exact fit ----
__global__ __launch_bounds__(512) void gemm_out(
    const u16* __restrict__ A, const u16* __restrict__ B,
    float* __restrict__ Out, const float* __restrict__ bias) {
  const int K = 2048;
  const int NS = K / 64;              // 32 K-tiles
  __shared__ u16 As[2][256 * 64];     // 32KB per buffer
  __shared__ u16 Bs[2][256 * 64];
  int tid = threadIdx.x;
  int l = tid & 63, w = tid >> 6;
  int lr = l & 15, lg = l >> 4;
  int wm = w >> 2, wn = w & 3;        // per-wave C = 128 x 64
  int p = blockIdx.x;
  int lidx = (p & 7) * 32 + (p >> 3); // 256 = 8 x 32 XCD-chunked
  int bx = lidx & 7, by = lidx >> 3;  // N tiles 8, M tiles 32
  int rowA = by * 256, colB = bx * 256;
  // staging: sweep i covers rows i*64+(tid>>3); 128B rows, slot swizzle ^(row&7)
  int srow = tid >> 3, sslot = tid & 7;
  int soff = ((sslot ^ (srow & 7))) * 8;
  const u16* ga = A + (size_t)(rowA + srow) * K + soff;
  const u16* gb = B + (size_t)(colB + srow) * K + soff;
  size_t sweep = (size_t)64 * K;
  f32x4 acc[8][4] = {};

  auto STAGE_A = [&](int kb, int bi) {
#pragma unroll
    for (int i = 0; i < 4; ++i)
      gload16(ga + i * sweep + kb, &As[bi][i * 4096 + tid * 8]);
  };
  auto STAGE_B = [&](int kb, int bi) {
#pragma unroll
    for (int i = 0; i < 4; ++i)
      gload16(gb + i * sweep + kb, &Bs[bi][i * 4096 + tid * 8]);
  };

  STAGE_A(0, 0);
  STAGE_B(0, 0);
  asm volatile("s_waitcnt vmcnt(0)" ::: "memory");
  __builtin_amdgcn_sched_barrier(0);
  __builtin_amdgcn_s_barrier();
  __builtin_amdgcn_sched_barrier(0);

  for (int t = 0; t < NS; ++t) {
    int cur = t & 1, nxt = cur ^ 1;
    bool pre = (t + 1 < NS);
    int kb1 = (t + 1) * 64;
    const u16* Ab = &As[cur][0];
    const u16* Bb = &Bs[cur][0];
    f16x8 afr[4][2], bfr[4][2];
    // ---- phase 0: read A(mh=0) + B(nh=0); stage A(t+1); MFMA mi0-3 x nj0-1
#pragma unroll
    for (int mi = 0; mi < 4; ++mi)
#pragma unroll
      for (int kk = 0; kk < 2; ++kk) {
        int row = wm * 128 + mi * 16 + lr;
        afr[mi][kk] = *(const f16x8*)&Ab[row * 64 + (((kk * 4 + lg) ^ (row & 7)) * 8)];
      }
#pragma unroll
    for (int nj = 0; nj < 2; ++nj)
#pragma unroll
      for (int kk = 0; kk < 2; ++kk) {
        int row = wn * 64 + nj * 16 + lr;
        bfr[nj][kk] = *(const f16x8*)&Bb[row * 64 + (((kk * 4 + lg) ^ (row & 7)) * 8)];
      }
    if (pre) STAGE_A(kb1, nxt);
    __builtin_amdgcn_s_setprio(1);
#pragma unroll
    for (int mi = 0; mi < 4; ++mi)
#pragma unroll
      for (int nj = 0; nj < 2; ++nj) {
        acc[mi][nj] = MFMA(afr[mi][0], bfr[nj][0], acc[mi][nj]);
        acc[mi][nj] = MFMA(afr[mi][1], bfr[nj][1], acc[mi][nj]);
      }
    __builtin_amdgcn_s_setprio(0);
    __builtin_amdgcn_s_barrier();
    // ---- phase 1: read B(nh=1); stage B(t+1); MFMA mi0-3 x nj2-3
#pragma unroll
    for (int nj = 2; nj < 4; ++nj)
#pragma unroll
      for (int kk = 0; kk < 2; ++kk) {
        int row = wn * 64 + nj * 16 + lr;
        bfr[nj][kk] = *(const f16x8*)&Bb[row * 64 + (((kk * 4 + lg) ^ (row & 7)) * 8)];
      }
    if (pre) STAGE_B(kb1, nxt);
    __builtin_amdgcn_s_setprio(1);
#pragma unroll
    for (int mi = 0; mi < 4; ++mi)
#pragma unroll
      for (int nj = 2; nj < 4; ++nj) {
        acc[mi][nj] = MFMA(afr[mi][0], bfr[nj][0], acc[mi][nj]);
        acc[mi][nj] = MFMA(afr[mi][1], bfr[nj][1], acc[mi][nj]);
      }
    __builtin_amdgcn_s_setprio(0);
    __builtin_amdgcn_s_barrier();
    // ---- phase 2: read A(mh=1); MFMA mi4-7 x nj0-1 (bfr held)
#pragma unroll
    for (int mi = 0; mi < 4; ++mi)
#pragma unroll
      for (int kk = 0; kk < 2; ++kk) {
        int row = wm * 128 + 64 + mi * 16 + lr;
        afr[mi][kk] = *(const f16x8*)&Ab[row * 64 + (((kk * 4 + lg) ^ (row & 7)) * 8)];
      }
    __builtin_amdgcn_s_setprio(1);
#pragma unroll
    for (int mi = 0; mi < 4; ++mi)
#pragma unroll
      for (int nj = 0; nj < 2; ++nj) {
        acc[4 + mi][nj] = MFMA(afr[mi][0], bfr[nj][0], acc[4 + mi][nj]);
        acc[4 + mi][nj] = MFMA(afr[mi][1], bfr[nj][1], acc[4 + mi][nj]);
      }
    __builtin_amdgcn_s_setprio(0);
    __builtin_amdgcn_s_barrier();
    // ---- phase 3: MFMA mi4-7 x nj2-3; tile-end drain + barrier
    __builtin_amdgcn_s_setprio(1);
#pragma unroll
    for (int mi = 0; mi < 4; ++mi)
#pragma unroll
      for (int nj = 2; nj < 4; ++nj) {
        acc[4 + mi][nj] = MFMA(afr[mi][0], bfr[nj][0], acc[4 + mi][nj]);
        acc[4 + mi][nj] = MFMA(afr[mi][1], bfr[nj][1], acc[4 + mi][nj]);
      }
    __builtin_amdgcn_s_setprio(0);
    asm volatile("s_waitcnt vmcnt(0)" ::: "memory");
    __builtin_amdgcn_sched_barrier(0);
    __builtin_amdgcn_s_barrier();
    __builtin_amdgcn_sched_barrier(0);
  }

#pragma unroll
  for (int mi = 0; mi < 8; ++mi) {
    int row0 = rowA + wm * 128 + mi * 16 + lg * 4;
#pragma unroll
    for (int nj = 0; nj < 4; ++nj) {
      int c = colB + wn * 64 + nj * 16 + lr;
      float bb = bias[c];
#pragma unroll
      for (int r = 0; r < 4; ++r)
        Out[(size_t)(row0 + r) * 2048 + c] = acc[mi][nj][r] + bb;
    }
  }
}

// ---------------- flash attention v7 + XCD-chunked swizzle (unchanged) ----------------
__global__ __launch_bounds__(512) void attn_kernel(
    const u16* __restrict__ Qf, const u16* __restrict__ Kf,
    const u16* __restrict__ VT, u16* __restrict__ Ch) {
  __shared__ u16 Ks[2][64 * 128];
  __shared__ u16 Vs[2][128 * 64];

  int tid = threadIdx.x;
  int w = tid >> 6, l = tid & 63;
  int lr = l & 15, lg = l >> 4;

  int p = blockIdx.x;
  int bid = (p & 7) * 64 + (p >> 3);
  int pair = bid & 7;
  int hg = (bid >> 3) & 3;
  int kvh = (bid >> 5) & 3;
  int b = bid >> 7;
  int h = kvh * 4 + hg;

  const u16* Kb = Kf + (size_t)(b * 2048) * 512 + kvh * 128;
  const u16* Vb = VT + (size_t)((b * 4 + kvh) * 128) * 2048;

  auto STAGE_K = [&](int t, int bufi) {
    int kv0 = t * 64;
#pragma unroll
    for (int pp = 0; pp < 2; ++pp) {
      int o16 = pp * 512 + tid;
      int krow = o16 >> 4;
      int kslot = ((o16 & 15) ^ (krow & 7)) * 8;
      gload16(Kb + (size_t)(kv0 + krow) * 512 + kslot, &Ks[bufi][o16 * 8]);
    }
  };
  auto STAGE_V = [&](int t, int bufi) {
    int kv0 = t * 64;
#pragma unroll
    for (int pp = 0; pp < 2; ++pp) {
      int o16 = pp * 512 + tid;
      int vrow = o16 >> 3;
      int vslot = ((o16 & 7) ^ (vrow & 7)) * 8;
      gload16(Vb + (size_t)vrow * 2048 + kv0 + vslot, &Vs[bufi][o16 * 8]);
    }
  };

  for (int pass = 0; pass < 2; ++pass) {
    int tIdx = pass == 0 ? (15 - pair) : pair;
    int q0 = tIdx * 128;
    int qr0 = q0 + w * 16;
    int nt = q0 / 64 + 2;

    size_t qbase = (size_t)(b * 2048 + qr0 + lr) * 2048 + h * 128 + lg * 8;
    f16x8 qf[4];
#pragma unroll
    for (int d = 0; d < 4; ++d)
      qf[d] = *(const f16x8*)(Qf + qbase + d * 32);

    f32x4 o[8] = {};
    float mrun = -3e38f;
    float lp = 0.f;

    STAGE_K(0, 0);
    STAGE_V(0, 0);
    asm volatile("s_waitcnt vmcnt(0)" ::: "memory");
    __builtin_amdgcn_sched_barrier(0);
    __builtin_amdgcn_s_barrier();
    __builtin_amdgcn_sched_barrier(0);

    int cur = 0;
    for (int t = 0; t < nt; ++t) {
      int kv0 = t * 64;
      bool more = (t + 1 < nt);
      if (more) {
        STAGE_K(t + 1, cur ^ 1);
        STAGE_V(t + 1, cur ^ 1);
      }
      bool compute = (kv0 <= qr0 + 15);

      if (compute) {
        f32x4 s[4] = {};
        __builtin_amdgcn_s_setprio(1);
#pragma unroll
        for (int d = 0; d < 4; ++d) {
#pragma unroll
          for (int n = 0; n < 4; ++n) {
            int row = n * 16 + lr;
            int sl = ((d * 4 + lg) ^ (row & 7)) * 8;
            f16x8 kf = *(const f16x8*)&Ks[cur][row * 128 + sl];
            s[n] = MFMA(kf, qf[d], s[n]);
          }
        }
        __builtin_amdgcn_s_setprio(0);
        if (kv0 + 63 > qr0) {
#pragma unroll
          for (int n = 0; n < 4; ++n)
#pragma unroll
            for (int r = 0; r < 4; ++r)
              if (kv0 + n * 16 + lg * 4 + r > qr0 + lr) s[n][r] = -3e38f;
        }
        float m0 = fmaxf(fmaxf(s[0][0], s[0][1]), fmaxf(s[0][2], s[0][3]));
        float m1 = fmaxf(fmaxf(s[1][0], s[1][1]), fmaxf(s[1][2], s[1][3]));
        float m2 = fmaxf(fmaxf(s[2][0], s[2][1]), fmaxf(s[2][2], s[2][3]));
        float m3 = fmaxf(fmaxf(s[3][0], s[3][1]), fmaxf(s[3][2], s[3][3]));
        float rowmax = fmaxf(fmaxf(m0, m1), fmaxf(m2, m3));
        if (__any(rowmax > mrun + 8.f)) {
          float tm = rowmax;
          tm = fmaxf(tm, __shfl_xor(tm, 16));
          tm = fmaxf(tm, __shfl_xor(tm, 32));
          float mn = fmaxf(mrun, tm);
          float alpha = __builtin_amdgcn_exp2f((mrun - mn) * LOG2E);
          mrun = mn;
          lp *= alpha;
#pragma unroll
          for (int dt = 0; dt < 8; ++dt)
#pragma unroll
            for (int r = 0; r < 4; ++r) o[dt][r] *= alpha;
        }
        float mL = mrun * LOG2E;
        float pv[4][4];
#pragma unroll
        for (int n = 0; n < 4; ++n)
#pragma unroll
          for (int r = 0; r < 4; ++r) {
            pv[n][r] = __builtin_amdgcn_exp2f(fmaf(s[n][r], LOG2E, -mL));
            lp += pv[n][r];
          }
        u32 A0[4], A1[4];
#pragma unroll
        for (int n = 0; n < 4; ++n) {
          A0[n] = pk2(pv[n][0], pv[n][1]);
          A1[n] = pk2(pv[n][2], pv[n][3]);
        }
        swap32(A0[0], A0[2]); swap32(A0[1], A0[3]);
        swap32(A1[0], A1[2]); swap32(A1[1], A1[3]);
        swap16(A0[0], A0[2]); swap16(A0[1], A0[3]);
        swap16(A1[0], A1[2]); swap16(A1[1], A1[3]);
        swap32(A0[0], A0[1]); swap32(A0[2], A0[3]);
        swap32(A1[0], A1[1]); swap32(A1[2], A1[3]);
        union { u32 w4[4]; f16x8 v; } P0, P1;
        P0.w4[0] = A0[0]; P0.w4[1] = A1[0]; P0.w4[2] = A0[2]; P0.w4[3] = A1[2];
        P1.w4[0] = A0[1]; P1.w4[1] = A1[1]; P1.w4[2] = A0[3]; P1.w4[3] = A1[3];
        __builtin_amdgcn_s_setprio(1);
#pragma unroll
        for (int n2 = 0; n2 < 2; ++n2) {
          f16x8 pf = n2 ? P1.v : P0.v;
#pragma unroll
          for (int dt = 0; dt < 8; ++dt) {
            int d = dt * 16 + lr;
            f16x8 vf = *(const f16x8*)&Vs[cur][d * 64 + (((n2 * 4 + lg) ^ (lr & 7)) * 8)];
            o[dt] = MFMA(vf, pf, o[dt]);
          }
        }
        __builtin_amdgcn_s_setprio(0);
      }
      asm volatile("s_waitcnt vmcnt(0) lgkmcnt(0)" ::: "memory");
      __builtin_amdgcn_sched_barrier(0);
      __builtin_amdgcn_s_barrier();
      __builtin_amdgcn_sched_barrier(0);
      cur ^= 1;
    }
    lp += __shfl_xor(lp, 16);
    lp += __shfl_xor(lp, 32);
    float inv = 1.0f / lp;
    size_t orow = (size_t)(b * 2048 + qr0 + lr) * 2048 + h * 128 + lg * 4;
#pragma unroll
    for (int dt = 0; dt < 8; ++dt) {
      uint2 pkt;
      pkt.x = pk2(o[dt][0] * inv, o[dt][1] * inv);
      pkt.y = pk2(o[dt][2] * inv, o[dt][3] * inv);
      *(uint2*)&Ch[orow + dt * 16] = pkt;
    }
  }
}

extern "C" void kernel_launch(void* const* d_in, const int* in_sizes, int n_in,
                              void* d_out, int out_size, void* d_ws, size_t ws_size,
                              hipStream_t stream) {
  const float* X  = (const float*)d_in[0];
  const float* qw = (const float*)d_in[1];
  const float* kw = (const float*)d_in[2];
  const float* vw = (const float*)d_in[3];
  const float* ow = (const float*)d_in[4];
  const float* ob = (const float*)d_in[5];
  float* Out = (float*)d_out;

  char* ws = (char*)d_ws;
  size_t off = 0;
  auto alloc = [&](size_t bytes) -> void* {
    void* p = ws + off;
    off += (bytes + 255) & ~(size_t)255;
    return p;
  };
  const size_t MK = (size_t)8192 * 2048;
  u16* Xf = (u16*)alloc(MK * 2);
  u16* Bt = (u16*)alloc((size_t)3072 * 2048 * 2);
  u16* OW = (u16*)alloc((size_t)2048 * 2048 * 2);
  u16* Qf = (u16*)alloc(MK * 2);
  u16* Kf = (u16*)alloc((size_t)8192 * 512 * 2);
  u16* VT = (u16*)alloc((size_t)8192 * 512 * 2);
  u16* Ch = (u16*)alloc(MK * 2);

  conv_f16<<<dim3(16384), dim3(256), 0, stream>>>((const float4*)X, Xf, (int)(MK / 4));
  dim3 tb(32, 8);
  transpose_f16<<<dim3(64, 64), tb, 0, stream>>>(qw, 2048, 2048, Bt, 0);
  transpose_f16<<<dim3(16, 64), tb, 0, stream>>>(kw, 2048, 512, Bt, 2048);
  transpose_f16<<<dim3(16, 64), tb, 0, stream>>>(vw, 2048, 512, Bt, 2560);
  transpose_f16<<<dim3(64, 64), tb, 0, stream>>>(ow, 2048, 2048, OW, 0);
  gemm_qkv<<<dim3(512), dim3(512), 0, stream>>>(Xf, Bt, Qf, Kf, VT);
  attn_kernel<<<dim3(512), dim3(512), 0, stream>>>(Qf, Kf, VT, Ch);
  gemm_out<<<dim3(256), dim3(512), 0, stream>>>(Ch, OW, Out, ob);
}

// Round 23
// 322.198 us; speedup vs baseline: 1.0982x; 1.0108x over previous
//
#include <hip/hip_runtime.h>

typedef unsigned short u16;
typedef unsigned int   u32;
typedef __attribute__((ext_vector_type(8))) _Float16 f16x8;
typedef __attribute__((ext_vector_type(2))) __fp16   fp16x2;
typedef __attribute__((ext_vector_type(4))) float    f32x4;

#define LOG2E 1.44269504088896340f

__device__ __forceinline__ u16 f2h(float x) {
  union { _Float16 h; u16 u; } c;
  c.h = (_Float16)x;
  return c.u;
}
__device__ __forceinline__ u32 pk2(float a, float b) {
  union { fp16x2 h; u32 u; } c;
  c.h = __builtin_amdgcn_cvt_pkrtz(a, b);
  return c.u;
}
__device__ __forceinline__ void swap32(u32& a, u32& b) {
  asm volatile("v_permlane32_swap_b32 %0, %1" : "+v"(a), "+v"(b));
}
__device__ __forceinline__ void swap16(u32& a, u32& b) {
  asm volatile("v_permlane16_swap_b32 %0, %1" : "+v"(a), "+v"(b));
}
__device__ __forceinline__ void gload16(const u16* g, u16* l) {
  __builtin_amdgcn_global_load_lds(
      (const __attribute__((address_space(1))) void*)g,
      (__attribute__((address_space(3))) void*)l, 16, 0, 0);
}
__device__ __forceinline__ f32x4 MFMA(f16x8 a, f16x8 b, f32x4 c) {
  return __builtin_amdgcn_mfma_f32_16x16x32_f16(a, b, c, 0, 0, 0);
}

// ---------------- elementwise fp32 -> fp16 ----------------
__global__ void conv_f16(const float4* __restrict__ src, u16* __restrict__ d, int n4) {
  int i = blockIdx.x * 256 + threadIdx.x;
  if (i >= n4) return;
  float4 v = src[i];
  union { u16 u[4]; uint2 q; } H;
  H.u[0] = f2h(v.x); H.u[1] = f2h(v.y); H.u[2] = f2h(v.z); H.u[3] = f2h(v.w);
  *(uint2*)&d[(size_t)i * 4] = H.q;
}

// ---------------- transpose [K x N] fp32 -> [N x 2048] fp16 ----------------
__global__ void transpose_f16(const float* __restrict__ src, int K, int N,
                              u16* __restrict__ d, int rowOff) {
  __shared__ float t[32][33];
  int n0 = blockIdx.x * 32, k0 = blockIdx.y * 32;
  int tx = threadIdx.x, ty = threadIdx.y;
#pragma unroll
  for (int i = 0; i < 4; ++i)
    t[ty + 8 * i][tx] = src[(size_t)(k0 + ty + 8 * i) * N + n0 + tx];
  __syncthreads();
#pragma unroll
  for (int i = 0; i < 4; ++i) {
    int n = n0 + ty + 8 * i, k = k0 + tx;
    d[(size_t)(rowOff + n) * 2048 + k] = f2h(t[tx][ty + 8 * i]);
  }
}

// ---- QKV GEMM v2: 256x256 tile, BK=64, 8 waves (2Mx4N, 128x64/wave),
//      4-phase deep pipeline, 128KB LDS, grid 384 = 32 x 12 (XCD-chunked) ----
__global__ __launch_bounds__(512) void gemm_qkv(
    const u16* __restrict__ A, const u16* __restrict__ B,
    u16* __restrict__ Qf, u16* __restrict__ Kf, u16* __restrict__ VT) {
  const int K = 2048;
  const int NS = K / 64;
  __shared__ u16 As[2][256 * 64];
  __shared__ u16 Bs[2][256 * 64];
  int tid = threadIdx.x;
  int l = tid & 63, w = tid >> 6;
  int lr = l & 15, lg = l >> 4;
  int wm = w >> 2, wn = w & 3;
  int p = blockIdx.x;
  int lidx = (p & 7) * 48 + (p >> 3);   // 384 = 8 x 48
  int bx = lidx % 12, by = lidx / 12;
  int rowA = by * 256, colB = bx * 256;
  int srow = tid >> 3, sslot = tid & 7;
  int soff = ((sslot ^ (srow & 7))) * 8;
  const u16* ga = A + (size_t)(rowA + srow) * K + soff;
  const u16* gb = B + (size_t)(colB + srow) * K + soff;
  size_t sweep = (size_t)64 * K;
  f32x4 acc[8][4] = {};

  auto STAGE_A = [&](int kb, int bi) {
#pragma unroll
    for (int i = 0; i < 4; ++i)
      gload16(ga + i * sweep + kb, &As[bi][i * 4096 + tid * 8]);
  };
  auto STAGE_B = [&](int kb, int bi) {
#pragma unroll
    for (int i = 0; i < 4; ++i)
      gload16(gb + i * sweep + kb, &Bs[bi][i * 4096 + tid * 8]);
  };

  STAGE_A(0, 0);
  STAGE_B(0, 0);
  asm volatile("s_waitcnt vmcnt(0)" ::: "memory");
  __builtin_amdgcn_sched_barrier(0);
  __builtin_amdgcn_s_barrier();
  __builtin_amdgcn_sched_barrier(0);

  for (int t = 0; t < NS; ++t) {
    int cur = t & 1, nxt = cur ^ 1;
    bool pre = (t + 1 < NS);
    int kb1 = (t + 1) * 64;
    const u16* Ab = &As[cur][0];
    const u16* Bb = &Bs[cur][0];
    f16x8 afr[4][2], bfr[4][2];
    // phase 0: read A(mh=0) + B(nh=0); stage A(t+1); MFMA mi0-3 x nj0-1
#pragma unroll
    for (int mi = 0; mi < 4; ++mi)
#pragma unroll
      for (int kk = 0; kk < 2; ++kk) {
        int row = wm * 128 + mi * 16 + lr;
        afr[mi][kk] = *(const f16x8*)&Ab[row * 64 + (((kk * 4 + lg) ^ (row & 7)) * 8)];
      }
#pragma unroll
    for (int nj = 0; nj < 2; ++nj)
#pragma unroll
      for (int kk = 0; kk < 2; ++kk) {
        int row = wn * 64 + nj * 16 + lr;
        bfr[nj][kk] = *(const f16x8*)&Bb[row * 64 + (((kk * 4 + lg) ^ (row & 7)) * 8)];
      }
    if (pre) STAGE_A(kb1, nxt);
    __builtin_amdgcn_s_setprio(1);
#pragma unroll
    for (int mi = 0; mi < 4; ++mi)
#pragma unroll
      for (int nj = 0; nj < 2; ++nj) {
        acc[mi][nj] = MFMA(afr[mi][0], bfr[nj][0], acc[mi][nj]);
        acc[mi][nj] = MFMA(afr[mi][1], bfr[nj][1], acc[mi][nj]);
      }
    __builtin_amdgcn_s_setprio(0);
    __builtin_amdgcn_s_barrier();
    // phase 1: read B(nh=1); stage B(t+1); MFMA mi0-3 x nj2-3
#pragma unroll
    for (int nj = 2; nj < 4; ++nj)
#pragma unroll
      for (int kk = 0; kk < 2; ++kk) {
        int row = wn * 64 + nj * 16 + lr;
        bfr[nj][kk] = *(const f16x8*)&Bb[row * 64 + (((kk * 4 + lg) ^ (row & 7)) * 8)];
      }
    if (pre) STAGE_B(kb1, nxt);
    __builtin_amdgcn_s_setprio(1);
#pragma unroll
    for (int mi = 0; mi < 4; ++mi)
#pragma unroll
      for (int nj = 2; nj < 4; ++nj) {
        acc[mi][nj] = MFMA(afr[mi][0], bfr[nj][0], acc[mi][nj]);
        acc[mi][nj] = MFMA(afr[mi][1], bfr[nj][1], acc[mi][nj]);
      }
    __builtin_amdgcn_s_setprio(0);
    __builtin_amdgcn_s_barrier();
    // phase 2: read A(mh=1); MFMA mi4-7 x nj0-1
#pragma unroll
    for (int mi = 0; mi < 4; ++mi)
#pragma unroll
      for (int kk = 0; kk < 2; ++kk) {
        int row = wm * 128 + 64 + mi * 16 + lr;
        afr[mi][kk] = *(const f16x8*)&Ab[row * 64 + (((kk * 4 + lg) ^ (row & 7)) * 8)];
      }
    __builtin_amdgcn_s_setprio(1);
#pragma unroll
    for (int mi = 0; mi < 4; ++mi)
#pragma unroll
      for (int nj = 0; nj < 2; ++nj) {
        acc[4 + mi][nj] = MFMA(afr[mi][0], bfr[nj][0], acc[4 + mi][nj]);
        acc[4 + mi][nj] = MFMA(afr[mi][1], bfr[nj][1], acc[4 + mi][nj]);
      }
    __builtin_amdgcn_s_setprio(0);
    __builtin_amdgcn_s_barrier();
    // phase 3: MFMA mi4-7 x nj2-3; tile-end drain + barrier
    __builtin_amdgcn_s_setprio(1);
#pragma unroll
    for (int mi = 0; mi < 4; ++mi)
#pragma unroll
      for (int nj = 2; nj < 4; ++nj) {
        acc[4 + mi][nj] = MFMA(afr[mi][0], bfr[nj][0], acc[4 + mi][nj]);
        acc[4 + mi][nj] = MFMA(afr[mi][1], bfr[nj][1], acc[4 + mi][nj]);
      }
    __builtin_amdgcn_s_setprio(0);
    asm volatile("s_waitcnt vmcnt(0)" ::: "memory");
    __builtin_amdgcn_sched_barrier(0);
    __builtin_amdgcn_s_barrier();
    __builtin_amdgcn_sched_barrier(0);
  }

#pragma unroll
  for (int mi = 0; mi < 8; ++mi) {
    int row0 = rowA + wm * 128 + mi * 16 + lg * 4;
#pragma unroll
    for (int nj = 0; nj < 4; ++nj) {
      int c = colB + wn * 64 + nj * 16 + lr;
      f32x4 v = acc[mi][nj];
      if (c < 2048) {
#pragma unroll
        for (int r = 0; r < 4; ++r)
          Qf[(size_t)(row0 + r) * 2048 + c] = f2h(v[r]);
      } else if (c < 2560) {
        int ck = c - 2048;
#pragma unroll
        for (int r = 0; r < 4; ++r)
          Kf[(size_t)(row0 + r) * 512 + ck] = f2h(v[r]);
      } else {
        int cv = c - 2560, kvh = cv >> 7, d = cv & 127;
#pragma unroll
        for (int r = 0; r < 4; ++r) {
          int row = row0 + r;
          int b = row >> 11, t2 = row & 2047;
          VT[((size_t)(b * 4 + kvh) * 128 + d) * 2048 + t2] = f2h(v[r]);
        }
      }
    }
  }
}

// ---- out-proj GEMM v2: 256x256 tile, BK=64, 4-phase (r22 proven) ----
__global__ __launch_bounds__(512) void gemm_out(
    const u16* __restrict__ A, const u16* __restrict__ B,
    float* __restrict__ Out, const float* __restrict__ bias) {
  const int K = 2048;
  const int NS = K / 64;
  __shared__ u16 As[2][256 * 64];
  __shared__ u16 Bs[2][256 * 64];
  int tid = threadIdx.x;
  int l = tid & 63, w = tid >> 6;
  int lr = l & 15, lg = l >> 4;
  int wm = w >> 2, wn = w & 3;
  int p = blockIdx.x;
  int lidx = (p & 7) * 32 + (p >> 3);
  int bx = lidx & 7, by = lidx >> 3;
  int rowA = by * 256, colB = bx * 256;
  int srow = tid >> 3, sslot = tid & 7;
  int soff = ((sslot ^ (srow & 7))) * 8;
  const u16* ga = A + (size_t)(rowA + srow) * K + soff;
  const u16* gb = B + (size_t)(colB + srow) * K + soff;
  size_t sweep = (size_t)64 * K;
  f32x4 acc[8][4] = {};

  auto STAGE_A = [&](int kb, int bi) {
#pragma unroll
    for (int i = 0; i < 4; ++i)
      gload16(ga + i * sweep + kb, &As[bi][i * 4096 + tid * 8]);
  };
  auto STAGE_B = [&](int kb, int bi) {
#pragma unroll
    for (int i = 0; i < 4; ++i)
      gload16(gb + i * sweep + kb, &Bs[bi][i * 4096 + tid * 8]);
  };

  STAGE_A(0, 0);
  STAGE_B(0, 0);
  asm volatile("s_waitcnt vmcnt(0)" ::: "memory");
  __builtin_amdgcn_sched_barrier(0);
  __builtin_amdgcn_s_barrier();
  __builtin_amdgcn_sched_barrier(0);

  for (int t = 0; t < NS; ++t) {
    int cur = t & 1, nxt = cur ^ 1;
    bool pre = (t + 1 < NS);
    int kb1 = (t + 1) * 64;
    const u16* Ab = &As[cur][0];
    const u16* Bb = &Bs[cur][0];
    f16x8 afr[4][2], bfr[4][2];
#pragma unroll
    for (int mi = 0; mi < 4; ++mi)
#pragma unroll
      for (int kk = 0; kk < 2; ++kk) {
        int row = wm * 128 + mi * 16 + lr;
        afr[mi][kk] = *(const f16x8*)&Ab[row * 64 + (((kk * 4 + lg) ^ (row & 7)) * 8)];
      }
#pragma unroll
    for (int nj = 0; nj < 2; ++nj)
#pragma unroll
      for (int kk = 0; kk < 2; ++kk) {
        int row = wn * 64 + nj * 16 + lr;
        bfr[nj][kk] = *(const f16x8*)&Bb[row * 64 + (((kk * 4 + lg) ^ (row & 7)) * 8)];
      }
    if (pre) STAGE_A(kb1, nxt);
    __builtin_amdgcn_s_setprio(1);
#pragma unroll
    for (int mi = 0; mi < 4; ++mi)
#pragma unroll
      for (int nj = 0; nj < 2; ++nj) {
        acc[mi][nj] = MFMA(afr[mi][0], bfr[nj][0], acc[mi][nj]);
        acc[mi][nj] = MFMA(afr[mi][1], bfr[nj][1], acc[mi][nj]);
      }
    __builtin_amdgcn_s_setprio(0);
    __builtin_amdgcn_s_barrier();
#pragma unroll
    for (int nj = 2; nj < 4; ++nj)
#pragma unroll
      for (int kk = 0; kk < 2; ++kk) {
        int row = wn * 64 + nj * 16 + lr;
        bfr[nj][kk] = *(const f16x8*)&Bb[row * 64 + (((kk * 4 + lg) ^ (row & 7)) * 8)];
      }
    if (pre) STAGE_B(kb1, nxt);
    __builtin_amdgcn_s_setprio(1);
#pragma unroll
    for (int mi = 0; mi < 4; ++mi)
#pragma unroll
      for (int nj = 2; nj < 4; ++nj) {
        acc[mi][nj] = MFMA(afr[mi][0], bfr[nj][0], acc[mi][nj]);
        acc[mi][nj] = MFMA(afr[mi][1], bfr[nj][1], acc[mi][nj]);
      }
    __builtin_amdgcn_s_setprio(0);
    __builtin_amdgcn_s_barrier();
#pragma unroll
    for (int mi = 0; mi < 4; ++mi)
#pragma unroll
      for (int kk = 0; kk < 2; ++kk) {
        int row = wm * 128 + 64 + mi * 16 + lr;
        afr[mi][kk] = *(const f16x8*)&Ab[row * 64 + (((kk * 4 + lg) ^ (row & 7)) * 8)];
      }
    __builtin_amdgcn_s_setprio(1);
#pragma unroll
    for (int mi = 0; mi < 4; ++mi)
#pragma unroll
      for (int nj = 0; nj < 2; ++nj) {
        acc[4 + mi][nj] = MFMA(afr[mi][0], bfr[nj][0], acc[4 + mi][nj]);
        acc[4 + mi][nj] = MFMA(afr[mi][1], bfr[nj][1], acc[4 + mi][nj]);
      }
    __builtin_amdgcn_s_setprio(0);
    __builtin_amdgcn_s_barrier();
    __builtin_amdgcn_s_setprio(1);
#pragma unroll
    for (int mi = 0; mi < 4; ++mi)
#pragma unroll
      for (int nj = 2; nj < 4; ++nj) {
        acc[4 + mi][nj] = MFMA(afr[mi][0], bfr[nj][0], acc[4 + mi][nj]);
        acc[4 + mi][nj] = MFMA(afr[mi][1], bfr[nj][1], acc[4 + mi][nj]);
      }
    __builtin_amdgcn_s_setprio(0);
    asm volatile("s_waitcnt vmcnt(0)" ::: "memory");
    __builtin_amdgcn_sched_barrier(0);
    __builtin_amdgcn_s_barrier();
    __builtin_amdgcn_sched_barrier(0);
  }

#pragma unroll
  for (int mi = 0; mi < 8; ++mi) {
    int row0 = rowA + wm * 128 + mi * 16 + lg * 4;
#pragma unroll
    for (int nj = 0; nj < 4; ++nj) {
      int c = colB + wn * 64 + nj * 16 + lr;
      float bb = bias[c];
#pragma unroll
      for (int r = 0; r < 4; ++r)
        Out[(size_t)(row0 + r) * 2048 + c] = acc[mi][nj][r] + bb;
    }
  }
}

// ---------------- flash attention v7 + XCD-chunked swizzle (unchanged) ----------------
__global__ __launch_bounds__(512) void attn_kernel(
    const u16* __restrict__ Qf, const u16* __restrict__ Kf,
    const u16* __restrict__ VT, u16* __restrict__ Ch) {
  __shared__ u16 Ks[2][64 * 128];
  __shared__ u16 Vs[2][128 * 64];

  int tid = threadIdx.x;
  int w = tid >> 6, l = tid & 63;
  int lr = l & 15, lg = l >> 4;

  int p = blockIdx.x;
  int bid = (p & 7) * 64 + (p >> 3);
  int pair = bid & 7;
  int hg = (bid >> 3) & 3;
  int kvh = (bid >> 5) & 3;
  int b = bid >> 7;
  int h = kvh * 4 + hg;

  const u16* Kb = Kf + (size_t)(b * 2048) * 512 + kvh * 128;
  const u16* Vb = VT + (size_t)((b * 4 + kvh) * 128) * 2048;

  auto STAGE_K = [&](int t, int bufi) {
    int kv0 = t * 64;
#pragma unroll
    for (int pp = 0; pp < 2; ++pp) {
      int o16 = pp * 512 + tid;
      int krow = o16 >> 4;
      int kslot = ((o16 & 15) ^ (krow & 7)) * 8;
      gload16(Kb + (size_t)(kv0 + krow) * 512 + kslot, &Ks[bufi][o16 * 8]);
    }
  };
  auto STAGE_V = [&](int t, int bufi) {
    int kv0 = t * 64;
#pragma unroll
    for (int pp = 0; pp < 2; ++pp) {
      int o16 = pp * 512 + tid;
      int vrow = o16 >> 3;
      int vslot = ((o16 & 7) ^ (vrow & 7)) * 8;
      gload16(Vb + (size_t)vrow * 2048 + kv0 + vslot, &Vs[bufi][o16 * 8]);
    }
  };

  for (int pass = 0; pass < 2; ++pass) {
    int tIdx = pass == 0 ? (15 - pair) : pair;
    int q0 = tIdx * 128;
    int qr0 = q0 + w * 16;
    int nt = q0 / 64 + 2;

    size_t qbase = (size_t)(b * 2048 + qr0 + lr) * 2048 + h * 128 + lg * 8;
    f16x8 qf[4];
#pragma unroll
    for (int d = 0; d < 4; ++d)
      qf[d] = *(const f16x8*)(Qf + qbase + d * 32);

    f32x4 o[8] = {};
    float mrun = -3e38f;
    float lp = 0.f;

    STAGE_K(0, 0);
    STAGE_V(0, 0);
    asm volatile("s_waitcnt vmcnt(0)" ::: "memory");
    __builtin_amdgcn_sched_barrier(0);
    __builtin_amdgcn_s_barrier();
    __builtin_amdgcn_sched_barrier(0);

    int cur = 0;
    for (int t = 0; t < nt; ++t) {
      int kv0 = t * 64;
      bool more = (t + 1 < nt);
      if (more) {
        STAGE_K(t + 1, cur ^ 1);
        STAGE_V(t + 1, cur ^ 1);
      }
      bool compute = (kv0 <= qr0 + 15);

      if (compute) {
        f32x4 s[4] = {};
        __builtin_amdgcn_s_setprio(1);
#pragma unroll
        for (int d = 0; d < 4; ++d) {
#pragma unroll
          for (int n = 0; n < 4; ++n) {
            int row = n * 16 + lr;
            int sl = ((d * 4 + lg) ^ (row & 7)) * 8;
            f16x8 kf = *(const f16x8*)&Ks[cur][row * 128 + sl];
            s[n] = MFMA(kf, qf[d], s[n]);
          }
        }
        __builtin_amdgcn_s_setprio(0);
        if (kv0 + 63 > qr0) {
#pragma unroll
          for (int n = 0; n < 4; ++n)
#pragma unroll
            for (int r = 0; r < 4; ++r)
              if (kv0 + n * 16 + lg * 4 + r > qr0 + lr) s[n][r] = -3e38f;
        }
        float m0 = fmaxf(fmaxf(s[0][0], s[0][1]), fmaxf(s[0][2], s[0][3]));
        float m1 = fmaxf(fmaxf(s[1][0], s[1][1]), fmaxf(s[1][2], s[1][3]));
        float m2 = fmaxf(fmaxf(s[2][0], s[2][1]), fmaxf(s[2][2], s[2][3]));
        float m3 = fmaxf(fmaxf(s[3][0], s[3][1]), fmaxf(s[3][2], s[3][3]));
        float rowmax = fmaxf(fmaxf(m0, m1), fmaxf(m2, m3));
        if (__any(rowmax > mrun + 8.f)) {
          float tm = rowmax;
          tm = fmaxf(tm, __shfl_xor(tm, 16));
          tm = fmaxf(tm, __shfl_xor(tm, 32));
          float mn = fmaxf(mrun, tm);
          float alpha = __builtin_amdgcn_exp2f((mrun - mn) * LOG2E);
          mrun = mn;
          lp *= alpha;
#pragma unroll
          for (int dt = 0; dt < 8; ++dt)
#pragma unroll
            for (int r = 0; r < 4; ++r) o[dt][r] *= alpha;
        }
        float mL = mrun * LOG2E;
        float pv[4][4];
#pragma unroll
        for (int n = 0; n < 4; ++n)
#pragma unroll
          for (int r = 0; r < 4; ++r) {
            pv[n][r] = __builtin_amdgcn_exp2f(fmaf(s[n][r], LOG2E, -mL));
            lp += pv[n][r];
          }
        u32 A0[4], A1[4];
#pragma unroll
        for (int n = 0; n < 4; ++n) {
          A0[n] = pk2(pv[n][0], pv[n][1]);
          A1[n] = pk2(pv[n][2], pv[n][3]);
        }
        swap32(A0[0], A0[2]); swap32(A0[1], A0[3]);
        swap32(A1[0], A1[2]); swap32(A1[1], A1[3]);
        swap16(A0[0], A0[2]); swap16(A0[1], A0[3]);
        swap16(A1[0], A1[2]); swap16(A1[1], A1[3]);
        swap32(A0[0], A0[1]); swap32(A0[2], A0[3]);
        swap32(A1[0], A1[1]); swap32(A1[2], A1[3]);
        union { u32 w4[4]; f16x8 v; } P0, P1;
        P0.w4[0] = A0[0]; P0.w4[1] = A1[0]; P0.w4[2] = A0[2]; P0.w4[3] = A1[2];
        P1.w4[0] = A0[1]; P1.w4[1] = A1[1]; P1.w4[2] = A0[3]; P1.w4[3] = A1[3];
        __builtin_amdgcn_s_setprio(1);
#pragma unroll
        for (int n2 = 0; n2 < 2; ++n2) {
          f16x8 pf = n2 ? P1.v : P0.v;
#pragma unroll
          for (int dt = 0; dt < 8; ++dt) {
            int d = dt * 16 + lr;
            f16x8 vf = *(const f16x8*)&Vs[cur][d * 64 + (((n2 * 4 + lg) ^ (lr & 7)) * 8)];
            o[dt] = MFMA(vf, pf, o[dt]);
          }
        }
        __builtin_amdgcn_s_setprio(0);
      }
      asm volatile("s_waitcnt vmcnt(0) lgkmcnt(0)" ::: "memory");
      __builtin_amdgcn_sched_barrier(0);
      __builtin_amdgcn_s_barrier();
      __builtin_amdgcn_sched_barrier(0);
      cur ^= 1;
    }
    lp += __shfl_xor(lp, 16);
    lp += __shfl_xor(lp, 32);
    float inv = 1.0f / lp;
    size_t orow = (size_t)(b * 2048 + qr0 + lr) * 2048 + h * 128 + lg * 4;
#pragma unroll
    for (int dt = 0; dt < 8; ++dt) {
      uint2 pkt;
      pkt.x = pk2(o[dt][0] * inv, o[dt][1] * inv);
      pkt.y = pk2(o[dt][2] * inv, o[dt][3] * inv);
      *(uint2*)&Ch[orow + dt * 16] = pkt;
    }
  }
}

extern "C" void kernel_launch(void* const* d_in, const int* in_sizes, int n_in,
                              void* d_out, int out_size, void* d_ws, size_t ws_size,
                              hipStream_t stream) {
  const float* X  = (const float*)d_in[0];
  const float* qw = (const float*)d_in[1];
  const float* kw = (const float*)d_in[2];
  const float* vw = (const float*)d_in[3];
  const float* ow = (const float*)d_in[4];
  const float* ob = (const float*)d_in[5];
  float* Out = (float*)d_out;

  char* ws = (char*)d_ws;
  size_t off = 0;
  auto alloc = [&](size_t bytes) -> void* {
    void* p = ws + off;
    off += (bytes + 255) & ~(size_t)255;
    return p;
  };
  const size_t MK = (size_t)8192 * 2048;
  u16* Xf = (u16*)alloc(MK * 2);
  u16* Bt = (u16*)alloc((size_t)3072 * 2048 * 2);
  u16* OW = (u16*)alloc((size_t)2048 * 2048 * 2);
  u16* Qf = (u16*)alloc(MK * 2);
  u16* Kf = (u16*)alloc((size_t)8192 * 512 * 2);
  u16* VT = (u16*)alloc((size_t)8192 * 512 * 2);
  u16* Ch = (u16*)alloc(MK * 2);

  conv_f16<<<dim3(16384), dim3(256), 0, stream>>>((const float4*)X, Xf, (int)(MK / 4));
  dim3 tb(32, 8);
  transpose_f16<<<dim3(64, 64), tb, 0, stream>>>(qw, 2048, 2048, Bt, 0);
  transpose_f16<<<dim3(16, 64), tb, 0, stream>>>(kw, 2048, 512, Bt, 2048);
  transpose_f16<<<dim3(16, 64), tb, 0, stream>>>(vw, 2048, 512, Bt, 2560);
  transpose_f16<<<dim3(64, 64), tb, 0, stream>>>(ow, 2048, 2048, OW, 0);
  gemm_qkv<<<dim3(384), dim3(512), 0, stream>>>(Xf, Bt, Qf, Kf, VT);
  attn_kernel<<<dim3(512), dim3(512), 0, stream>>>(Qf, Kf, VT, Ch);
  gemm_out<<<dim3(256), dim3(512), 0, stream>>>(Ch, OW, Out, ob);
}

// Round 24
// 321.648 us; speedup vs baseline: 1.1001x; 1.0017x over previous
//
#include <hip/hip_runtime.h>

typedef unsigned short u16;
typedef unsigned int   u32;
typedef __attribute__((ext_vector_type(8))) _Float16 f16x8;
typedef __attribute__((ext_vector_type(2))) __fp16   fp16x2;
typedef __attribute__((ext_vector_type(4))) float    f32x4;

#define LOG2E 1.44269504088896340f

__device__ __forceinline__ u16 f2h(float x) {
  union { _Float16 h; u16 u; } c;
  c.h = (_Float16)x;
  return c.u;
}
__device__ __forceinline__ u32 pk2(float a, float b) {
  union { fp16x2 h; u32 u; } c;
  c.h = __builtin_amdgcn_cvt_pkrtz(a, b);
  return c.u;
}
__device__ __forceinline__ void swap32(u32& a, u32& b) {
  asm volatile("v_permlane32_swap_b32 %0, %1" : "+v"(a), "+v"(b));
}
__device__ __forceinline__ void swap16(u32& a, u32& b) {
  asm volatile("v_permlane16_swap_b32 %0, %1" : "+v"(a), "+v"(b));
}
__device__ __forceinline__ void gload16(const u16* g, u16* l) {
  __builtin_amdgcn_global_load_lds(
      (const __attribute__((address_space(1))) void*)g,
      (__attribute__((address_space(3))) void*)l, 16, 0, 0);
}
__device__ __forceinline__ f32x4 MFMA(f16x8 a, f16x8 b, f32x4 c) {
  return __builtin_amdgcn_mfma_f32_16x16x32_f16(a, b, c, 0, 0, 0);
}

// ---------------- elementwise fp32 -> fp16 ----------------
__global__ void conv_f16(const float4* __restrict__ src, u16* __restrict__ d, int n4) {
  int i = blockIdx.x * 256 + threadIdx.x;
  if (i >= n4) return;
  float4 v = src[i];
  union { u16 u[4]; uint2 q; } H;
  H.u[0] = f2h(v.x); H.u[1] = f2h(v.y); H.u[2] = f2h(v.z); H.u[3] = f2h(v.w);
  *(uint2*)&d[(size_t)i * 4] = H.q;
}

// ---------------- transpose [K x N] fp32 -> [N x 2048] fp16 ----------------
__global__ void transpose_f16(const float* __restrict__ src, int K, int N,
                              u16* __restrict__ d, int rowOff) {
  __shared__ float t[32][33];
  int n0 = blockIdx.x * 32, k0 = blockIdx.y * 32;
  int tx = threadIdx.x, ty = threadIdx.y;
#pragma unroll
  for (int i = 0; i < 4; ++i)
    t[ty + 8 * i][tx] = src[(size_t)(k0 + ty + 8 * i) * N + n0 + tx];
  __syncthreads();
#pragma unroll
  for (int i = 0; i < 4; ++i) {
    int n = n0 + ty + 8 * i, k = k0 + tx;
    d[(size_t)(rowOff + n) * 2048 + k] = f2h(t[tx][ty + 8 * i]);
  }
}

// ---- QKV GEMM: r21 proven best (256x128, 3-buf counted, ONE barrier/step,
//      PERSISTENT 768 jobs on 512-block grid; 117us, MfmaUtil 40%) ----
__global__ __launch_bounds__(512) void gemm_qkv(
    const u16* __restrict__ A, const u16* __restrict__ B,
    u16* __restrict__ Qf, u16* __restrict__ Kf, u16* __restrict__ VT) {
  const int K = 2048;
  const int NS = K / 32;
  __shared__ u16 As[3][256 * 32];
  __shared__ u16 Bs[3][128 * 32];
  int tid = threadIdx.x;
  int l = tid & 63, w = tid >> 6;
  int lr = l & 15, lg = l >> 4;
  int wr = w >> 1, wc = w & 1;
  int r0 = tid >> 2;
  int ssrc = (((tid & 3) ^ ((r0 >> 1) & 3))) * 8;
  size_t half = (size_t)128 * K;
  int swz = (lr >> 1) & 3;
  int aoff = (wr * 64 + lr) * 32 + (lg ^ swz) * 8;
  int boff = (wc * 64 + lr) * 32 + (lg ^ swz) * 8;

  for (int job = blockIdx.x; job < 768; job += 512) {
    int lidx = (job & 7) * 96 + (job >> 3);
    int bx = lidx % 24, by = lidx / 24;
    int rowA = by * 256, colB = bx * 128;
    const u16* ga = A + (size_t)(rowA + r0) * K + ssrc;
    const u16* gb = B + (size_t)(colB + r0) * K + ssrc;
    f32x4 acc[4][4] = {};

    gload16(ga, &As[0][tid * 8]);
    gload16(ga + half, &As[0][4096 + tid * 8]);
    gload16(gb, &Bs[0][tid * 8]);
    gload16(ga + 32, &As[1][tid * 8]);
    gload16(ga + 32 + half, &As[1][4096 + tid * 8]);
    gload16(gb + 32, &Bs[1][tid * 8]);
    asm volatile("s_waitcnt vmcnt(3)" ::: "memory");
    __builtin_amdgcn_sched_barrier(0);
    __builtin_amdgcn_s_barrier();
    __builtin_amdgcn_sched_barrier(0);

    for (int t = 0; t < NS; ++t) {
      int cur = t % 3, nxt = (t + 2) % 3;
      bool pre = (t + 2 < NS);
      int kb2 = (t + 2) * 32;
      f16x8 ah[4], bh[4];
#pragma unroll
      for (int i = 0; i < 4; ++i)
        ah[i] = *(const f16x8*)&As[cur][aoff + i * 512];
#pragma unroll
      for (int j = 0; j < 4; ++j)
        bh[j] = *(const f16x8*)&Bs[cur][boff + j * 512];
      if (pre) {
        gload16(ga + kb2, &As[nxt][tid * 8]);
        gload16(ga + kb2 + half, &As[nxt][4096 + tid * 8]);
        gload16(gb + kb2, &Bs[nxt][tid * 8]);
      }
      __builtin_amdgcn_s_setprio(1);
#pragma unroll
      for (int i = 0; i < 4; ++i)
#pragma unroll
        for (int j = 0; j < 4; ++j)
          acc[i][j] = MFMA(ah[i], bh[j], acc[i][j]);
      __builtin_amdgcn_s_setprio(0);
      if (pre) {
        asm volatile("s_waitcnt vmcnt(3)" ::: "memory");
      } else {
        asm volatile("s_waitcnt vmcnt(0)" ::: "memory");
      }
      __builtin_amdgcn_sched_barrier(0);
      __builtin_amdgcn_s_barrier();
      __builtin_amdgcn_sched_barrier(0);
    }

#pragma unroll
    for (int i = 0; i < 4; ++i) {
      int row0 = rowA + wr * 64 + i * 16 + lg * 4;
#pragma unroll
      for (int j = 0; j < 4; ++j) {
        int c = colB + wc * 64 + j * 16 + lr;
        f32x4 v = acc[i][j];
        if (c < 2048) {
#pragma unroll
          for (int r = 0; r < 4; ++r)
            Qf[(size_t)(row0 + r) * 2048 + c] = f2h(v[r]);
        } else if (c < 2560) {
          int ck = c - 2048;
#pragma unroll
          for (int r = 0; r < 4; ++r)
            Kf[(size_t)(row0 + r) * 512 + ck] = f2h(v[r]);
        } else {
          int cv = c - 2560, kvh = cv >> 7, d = cv & 127;
          int b = row0 >> 11, t2 = row0 & 2047;
          union { u16 u[4]; uint2 q; } P;
#pragma unroll
          for (int r = 0; r < 4; ++r) P.u[r] = f2h(v[r]);
          *(uint2*)&VT[((size_t)(b * 4 + kvh) * 128 + d) * 2048 + t2] = P.q;
        }
      }
    }
    __builtin_amdgcn_s_barrier();
    __builtin_amdgcn_sched_barrier(0);
  }
}

// ---- out-proj GEMM v2: 256x256 tile, BK=64, 4-phase (r22 proven, ~54us) ----
__global__ __launch_bounds__(512) void gemm_out(
    const u16* __restrict__ A, const u16* __restrict__ B,
    float* __restrict__ Out, const float* __restrict__ bias) {
  const int K = 2048;
  const int NS = K / 64;
  __shared__ u16 As[2][256 * 64];
  __shared__ u16 Bs[2][256 * 64];
  int tid = threadIdx.x;
  int l = tid & 63, w = tid >> 6;
  int lr = l & 15, lg = l >> 4;
  int wm = w >> 2, wn = w & 3;
  int p = blockIdx.x;
  int lidx = (p & 7) * 32 + (p >> 3);
  int bx = lidx & 7, by = lidx >> 3;
  int rowA = by * 256, colB = bx * 256;
  int srow = tid >> 3, sslot = tid & 7;
  int soff = ((sslot ^ (srow & 7))) * 8;
  const u16* ga = A + (size_t)(rowA + srow) * K + soff;
  const u16* gb = B + (size_t)(colB + srow) * K + soff;
  size_t sweep = (size_t)64 * K;
  f32x4 acc[8][4] = {};

  auto STAGE_A = [&](int kb, int bi) {
#pragma unroll
    for (int i = 0; i < 4; ++i)
      gload16(ga + i * sweep + kb, &As[bi][i * 4096 + tid * 8]);
  };
  auto STAGE_B = [&](int kb, int bi) {
#pragma unroll
    for (int i = 0; i < 4; ++i)
      gload16(gb + i * sweep + kb, &Bs[bi][i * 4096 + tid * 8]);
  };

  STAGE_A(0, 0);
  STAGE_B(0, 0);
  asm volatile("s_waitcnt vmcnt(0)" ::: "memory");
  __builtin_amdgcn_sched_barrier(0);
  __builtin_amdgcn_s_barrier();
  __builtin_amdgcn_sched_barrier(0);

  for (int t = 0; t < NS; ++t) {
    int cur = t & 1, nxt = cur ^ 1;
    bool pre = (t + 1 < NS);
    int kb1 = (t + 1) * 64;
    const u16* Ab = &As[cur][0];
    const u16* Bb = &Bs[cur][0];
    f16x8 afr[4][2], bfr[4][2];
#pragma unroll
    for (int mi = 0; mi < 4; ++mi)
#pragma unroll
      for (int kk = 0; kk < 2; ++kk) {
        int row = wm * 128 + mi * 16 + lr;
        afr[mi][kk] = *(const f16x8*)&Ab[row * 64 + (((kk * 4 + lg) ^ (row & 7)) * 8)];
      }
#pragma unroll
    for (int nj = 0; nj < 2; ++nj)
#pragma unroll
      for (int kk = 0; kk < 2; ++kk) {
        int row = wn * 64 + nj * 16 + lr;
        bfr[nj][kk] = *(const f16x8*)&Bb[row * 64 + (((kk * 4 + lg) ^ (row & 7)) * 8)];
      }
    if (pre) STAGE_A(kb1, nxt);
    __builtin_amdgcn_s_setprio(1);
#pragma unroll
    for (int mi = 0; mi < 4; ++mi)
#pragma unroll
      for (int nj = 0; nj < 2; ++nj) {
        acc[mi][nj] = MFMA(afr[mi][0], bfr[nj][0], acc[mi][nj]);
        acc[mi][nj] = MFMA(afr[mi][1], bfr[nj][1], acc[mi][nj]);
      }
    __builtin_amdgcn_s_setprio(0);
    __builtin_amdgcn_s_barrier();
#pragma unroll
    for (int nj = 2; nj < 4; ++nj)
#pragma unroll
      for (int kk = 0; kk < 2; ++kk) {
        int row = wn * 64 + nj * 16 + lr;
        bfr[nj][kk] = *(const f16x8*)&Bb[row * 64 + (((kk * 4 + lg) ^ (row & 7)) * 8)];
      }
    if (pre) STAGE_B(kb1, nxt);
    __builtin_amdgcn_s_setprio(1);
#pragma unroll
    for (int mi = 0; mi < 4; ++mi)
#pragma unroll
      for (int nj = 2; nj < 4; ++nj) {
        acc[mi][nj] = MFMA(afr[mi][0], bfr[nj][0], acc[mi][nj]);
        acc[mi][nj] = MFMA(afr[mi][1], bfr[nj][1], acc[mi][nj]);
      }
    __builtin_amdgcn_s_setprio(0);
    __builtin_amdgcn_s_barrier();
#pragma unroll
    for (int mi = 0; mi < 4; ++mi)
#pragma unroll
      for (int kk = 0; kk < 2; ++kk) {
        int row = wm * 128 + 64 + mi * 16 + lr;
        afr[mi][kk] = *(const f16x8*)&Ab[row * 64 + (((kk * 4 + lg) ^ (row & 7)) * 8)];
      }
    __builtin_amdgcn_s_setprio(1);
#pragma unroll
    for (int mi = 0; mi < 4; ++mi)
#pragma unroll
      for (int nj = 0; nj < 2; ++nj) {
        acc[4 + mi][nj] = MFMA(afr[mi][0], bfr[nj][0], acc[4 + mi][nj]);
        acc[4 + mi][nj] = MFMA(afr[mi][1], bfr[nj][1], acc[4 + mi][nj]);
      }
    __builtin_amdgcn_s_setprio(0);
    __builtin_amdgcn_s_barrier();
    __builtin_amdgcn_s_setprio(1);
#pragma unroll
    for (int mi = 0; mi < 4; ++mi)
#pragma unroll
      for (int nj = 2; nj < 4; ++nj) {
        acc[4 + mi][nj] = MFMA(afr[mi][0], bfr[nj][0], acc[4 + mi][nj]);
        acc[4 + mi][nj] = MFMA(afr[mi][1], bfr[nj][1], acc[4 + mi][nj]);
      }
    __builtin_amdgcn_s_setprio(0);
    asm volatile("s_waitcnt vmcnt(0)" ::: "memory");
    __builtin_amdgcn_sched_barrier(0);
    __builtin_amdgcn_s_barrier();
    __builtin_amdgcn_sched_barrier(0);
  }

#pragma unroll
  for (int mi = 0; mi < 8; ++mi) {
    int row0 = rowA + wm * 128 + mi * 16 + lg * 4;
#pragma unroll
    for (int nj = 0; nj < 4; ++nj) {
      int c = colB + wn * 64 + nj * 16 + lr;
      float bb = bias[c];
#pragma unroll
      for (int r = 0; r < 4; ++r)
        Out[(size_t)(row0 + r) * 2048 + c] = acc[mi][nj][r] + bb;
    }
  }
}

// ---------------- flash attention v7 + XCD-chunked swizzle ----------------
__global__ __launch_bounds__(512) void attn_kernel(
    const u16* __restrict__ Qf, const u16* __restrict__ Kf,
    const u16* __restrict__ VT, u16* __restrict__ Ch) {
  __shared__ u16 Ks[2][64 * 128];
  __shared__ u16 Vs[2][128 * 64];

  int tid = threadIdx.x;
  int w = tid >> 6, l = tid & 63;
  int lr = l & 15, lg = l >> 4;

  int p = blockIdx.x;
  int bid = (p & 7) * 64 + (p >> 3);
  int pair = bid & 7;
  int hg = (bid >> 3) & 3;
  int kvh = (bid >> 5) & 3;
  int b = bid >> 7;
  int h = kvh * 4 + hg;

  const u16* Kb = Kf + (size_t)(b * 2048) * 512 + kvh * 128;
  const u16* Vb = VT + (size_t)((b * 4 + kvh) * 128) * 2048;

  auto STAGE_K = [&](int t, int bufi) {
    int kv0 = t * 64;
#pragma unroll
    for (int pp = 0; pp < 2; ++pp) {
      int o16 = pp * 512 + tid;
      int krow = o16 >> 4;
      int kslot = ((o16 & 15) ^ (krow & 7)) * 8;
      gload16(Kb + (size_t)(kv0 + krow) * 512 + kslot, &Ks[bufi][o16 * 8]);
    }
  };
  auto STAGE_V = [&](int t, int bufi) {
    int kv0 = t * 64;
#pragma unroll
    for (int pp = 0; pp < 2; ++pp) {
      int o16 = pp * 512 + tid;
      int vrow = o16 >> 3;
      int vslot = ((o16 & 7) ^ (vrow & 7)) * 8;
      gload16(Vb + (size_t)vrow * 2048 + kv0 + vslot, &Vs[bufi][o16 * 8]);
    }
  };

  for (int pass = 0; pass < 2; ++pass) {
    int tIdx = pass == 0 ? (15 - pair) : pair;
    int q0 = tIdx * 128;
    int qr0 = q0 + w * 16;
    int nt = q0 / 64 + 2;

    size_t qbase = (size_t)(b * 2048 + qr0 + lr) * 2048 + h * 128 + lg * 8;
    f16x8 qf[4];
#pragma unroll
    for (int d = 0; d < 4; ++d)
      qf[d] = *(const f16x8*)(Qf + qbase + d * 32);

    f32x4 o[8] = {};
    float mrun = -3e38f;
    float lp = 0.f;

    STAGE_K(0, 0);
    STAGE_V(0, 0);
    asm volatile("s_waitcnt vmcnt(0)" ::: "memory");
    __builtin_amdgcn_sched_barrier(0);
    __builtin_amdgcn_s_barrier();
    __builtin_amdgcn_sched_barrier(0);

    int cur = 0;
    for (int t = 0; t < nt; ++t) {
      int kv0 = t * 64;
      bool more = (t + 1 < nt);
      if (more) {
        STAGE_K(t + 1, cur ^ 1);
        STAGE_V(t + 1, cur ^ 1);
      }
      bool compute = (kv0 <= qr0 + 15);

      if (compute) {
        f32x4 s[4] = {};
        __builtin_amdgcn_s_setprio(1);
#pragma unroll
        for (int d = 0; d < 4; ++d) {
#pragma unroll
          for (int n = 0; n < 4; ++n) {
            int row = n * 16 + lr;
            int sl = ((d * 4 + lg) ^ (row & 7)) * 8;
            f16x8 kf = *(const f16x8*)&Ks[cur][row * 128 + sl];
            s[n] = MFMA(kf, qf[d], s[n]);
          }
        }
        __builtin_amdgcn_s_setprio(0);
        if (kv0 + 63 > qr0) {
#pragma unroll
          for (int n = 0; n < 4; ++n)
#pragma unroll
            for (int r = 0; r < 4; ++r)
              if (kv0 + n * 16 + lg * 4 + r > qr0 + lr) s[n][r] = -3e38f;
        }
        float m0 = fmaxf(fmaxf(s[0][0], s[0][1]), fmaxf(s[0][2], s[0][3]));
        float m1 = fmaxf(fmaxf(s[1][0], s[1][1]), fmaxf(s[1][2], s[1][3]));
        float m2 = fmaxf(fmaxf(s[2][0], s[2][1]), fmaxf(s[2][2], s[2][3]));
        float m3 = fmaxf(fmaxf(s[3][0], s[3][1]), fmaxf(s[3][2], s[3][3]));
        float rowmax = fmaxf(fmaxf(m0, m1), fmaxf(m2, m3));
        if (__any(rowmax > mrun + 8.f)) {
          float tm = rowmax;
          tm = fmaxf(tm, __shfl_xor(tm, 16));
          tm = fmaxf(tm, __shfl_xor(tm, 32));
          float mn = fmaxf(mrun, tm);
          float alpha = __builtin_amdgcn_exp2f((mrun - mn) * LOG2E);
          mrun = mn;
          lp *= alpha;
#pragma unroll
          for (int dt = 0; dt < 8; ++dt)
#pragma unroll
            for (int r = 0; r < 4; ++r) o[dt][r] *= alpha;
        }
        float mL = mrun * LOG2E;
        float pv[4][4];
#pragma unroll
        for (int n = 0; n < 4; ++n)
#pragma unroll
          for (int r = 0; r < 4; ++r) {
            pv[n][r] = __builtin_amdgcn_exp2f(fmaf(s[n][r], LOG2E, -mL));
            lp += pv[n][r];
          }
        u32 A0[4], A1[4];
#pragma unroll
        for (int n = 0; n < 4; ++n) {
          A0[n] = pk2(pv[n][0], pv[n][1]);
          A1[n] = pk2(pv[n][2], pv[n][3]);
        }
        swap32(A0[0], A0[2]); swap32(A0[1], A0[3]);
        swap32(A1[0], A1[2]); swap32(A1[1], A1[3]);
        swap16(A0[0], A0[2]); swap16(A0[1], A0[3]);
        swap16(A1[0], A1[2]); swap16(A1[1], A1[3]);
        swap32(A0[0], A0[1]); swap32(A0[2], A0[3]);
        swap32(A1[0], A1[1]); swap32(A1[2], A1[3]);
        union { u32 w4[4]; f16x8 v; } P0, P1;
        P0.w4[0] = A0[0]; P0.w4[1] = A1[0]; P0.w4[2] = A0[2]; P0.w4[3] = A1[2];
        P1.w4[0] = A0[1]; P1.w4[1] = A1[1]; P1.w4[2] = A0[3]; P1.w4[3] = A1[3];
        __builtin_amdgcn_s_setprio(1);
#pragma unroll
        for (int n2 = 0; n2 < 2; ++n2) {
          f16x8 pf = n2 ? P1.v : P0.v;
#pragma unroll
          for (int dt = 0; dt < 8; ++dt) {
            int d = dt * 16 + lr;
            f16x8 vf = *(const f16x8*)&Vs[cur][d * 64 + (((n2 * 4 + lg) ^ (lr & 7)) * 8)];
            o[dt] = MFMA(vf, pf, o[dt]);
          }
        }
        __builtin_amdgcn_s_setprio(0);
      }
      asm volatile("s_waitcnt vmcnt(0) lgkmcnt(0)" ::: "memory");
      __builtin_amdgcn_sched_barrier(0);
      __builtin_amdgcn_s_barrier();
      __builtin_amdgcn_sched_barrier(0);
      cur ^= 1;
    }
    lp += __shfl_xor(lp, 16);
    lp += __shfl_xor(lp, 32);
    float inv = 1.0f / lp;
    size_t orow = (size_t)(b * 2048 + qr0 + lr) * 2048 + h * 128 + lg * 4;
#pragma unroll
    for (int dt = 0; dt < 8; ++dt) {
      uint2 pkt;
      pkt.x = pk2(o[dt][0] * inv, o[dt][1] * inv);
      pkt.y = pk2(o[dt][2] * inv, o[dt][3] * inv);
      *(uint2*)&Ch[orow + dt * 16] = pkt;
    }
  }
}

extern "C" void kernel_launch(void* const* d_in, const int* in_sizes, int n_in,
                              void* d_out, int out_size, void* d_ws, size_t ws_size,
                              hipStream_t stream) {
  const float* X  = (const float*)d_in[0];
  const float* qw = (const float*)d_in[1];
  const float* kw = (const float*)d_in[2];
  const float* vw = (const float*)d_in[3];
  const float* ow = (const float*)d_in[4];
  const float* ob = (const float*)d_in[5];
  float* Out = (float*)d_out;

  char* ws = (char*)d_ws;
  size_t off = 0;
  auto alloc = [&](size_t bytes) -> void* {
    void* p = ws + off;
    off += (bytes + 255) & ~(size_t)255;
    return p;
  };
  const size_t MK = (size_t)8192 * 2048;
  u16* Xf = (u16*)alloc(MK * 2);
  u16* Bt = (u16*)alloc((size_t)3072 * 2048 * 2);
  u16* OW = (u16*)alloc((size_t)2048 * 2048 * 2);
  u16* Qf = (u16*)alloc(MK * 2);
  u16* Kf = (u16*)alloc((size_t)8192 * 512 * 2);
  u16* VT = (u16*)alloc((size_t)8192 * 512 * 2);
  u16* Ch = (u16*)alloc(MK * 2);

  conv_f16<<<dim3(16384), dim3(256), 0, stream>>>((const float4*)X, Xf, (int)(MK / 4));
  dim3 tb(32, 8);
  transpose_f16<<<dim3(64, 64), tb, 0, stream>>>(qw, 2048, 2048, Bt, 0);
  transpose_f16<<<dim3(16, 64), tb, 0, stream>>>(kw, 2048, 512, Bt, 2048);
  transpose_f16<<<dim3(16, 64), tb, 0, stream>>>(vw, 2048, 512, Bt, 2560);
  transpose_f16<<<dim3(64, 64), tb, 0, stream>>>(ow, 2048, 2048, OW, 0);
  gemm_qkv<<<dim3(512), dim3(512), 0, stream>>>(Xf, Bt, Qf, Kf, VT);
  attn_kernel<<<dim3(512), dim3(512), 0, stream>>>(Qf, Kf, VT, Ch);
  gemm_out<<<dim3(256), dim3(512), 0, stream>>>(Ch, OW, Out, ob);
}